// Round 1
// baseline (9600.932 us; speedup 1.0000x reference)
//
#include <hip/hip_runtime.h>

#define NS 128
#define NV 64
#define TPC 192
#define NBASIS 16
#define HID 128
#define WOUT 384
#define NNODE 16000
#define NEDGE 256000
#define EPB 32

__device__ __forceinline__ float silu_f(float x) { return x / (1.0f + __expf(-x)); }

// ---------------- Kernel A: x_s = s@W_pre_s/sqrt(128)+b ; x_v = v@W_pre_v/sqrt(64)
__global__ __launch_bounds__(256) void node_pre(
    const float* __restrict__ node_feat, const float* __restrict__ Wps,
    const float* __restrict__ bps, const float* __restrict__ Wpv,
    float* __restrict__ x_s, float* __restrict__ x_v) {
  const int n = blockIdx.x;
  const int t = threadIdx.x;
  __shared__ float s_sh[NS];
  __shared__ float v_sh[NV * 3];
  const float* row = node_feat + (size_t)n * 320;
  for (int i = t; i < 320; i += 256) {
    float val = row[i];
    if (i < NS) s_sh[i] = val; else v_sh[i - NS] = val;
  }
  __syncthreads();
  for (int o = t; o < 320; o += 256) {
    if (o < NS) {
      float a = 0.f;
      #pragma unroll 8
      for (int u = 0; u < NS; ++u) a = fmaf(s_sh[u], Wps[u * NS + o], a);
      x_s[(size_t)n * NS + o] = a * 0.08838834764831845f + bps[o];
    } else {
      const int q = o - NS;
      const int vch = q / 3, c = q - vch * 3;
      float a = 0.f;
      #pragma unroll 8
      for (int u = 0; u < NV; ++u) a = fmaf(v_sh[u * 3 + c], Wpv[u * NV + vch], a);
      x_v[(size_t)n * (NV * 3) + q] = a * 0.125f;
    }
  }
}

// ---------------- Edge epilogue: message algebra + atomic scatter
__device__ __forceinline__ void edge_epilogue(
    const float* __restrict__ acc, int cbase, int src, int dst,
    float r0, float r1x, float r1y, float r1z,
    const float* __restrict__ b2, const float* __restrict__ x_s,
    const float* __restrict__ x_v, float* __restrict__ acc_s,
    float* __restrict__ acc_v) {
  if (cbase < 128) {              // w_ss0: msg_s[:, j] = w * s_j * r0
    const float* sj = x_s + (size_t)src * NS + cbase;
    float* ap = acc_s + (size_t)dst * TPC + cbase;
    #pragma unroll
    for (int i = 0; i < 8; ++i) {
      float w = acc[i] + b2[cbase + i];
      unsafeAtomicAdd(ap + i, w * sj[i] * r0);
    }
  } else if (cbase < 192) {       // w_vv0: msg_s[:, 128+u] = w * <v_j[u], r1> / sqrt(3)
    const int u0 = cbase - 128;
    #pragma unroll
    for (int i = 0; i < 8; ++i) {
      const int u = u0 + i;
      const float* vj = x_v + (size_t)src * (NV * 3) + u * 3;
      float vd = vj[0] * r1x + vj[1] * r1y + vj[2] * r1z;
      float w = acc[i] + b2[cbase + i];
      unsafeAtomicAdd(acc_s + (size_t)dst * TPC + NS + u, w * vd * 0.5773502691896258f);
    }
  } else if (cbase < 320) {       // w_sv1: msg_v[:, sj, c] = w * s_j * r1[c]
    const int s0 = cbase - 192;
    #pragma unroll
    for (int i = 0; i < 8; ++i) {
      const int sji = s0 + i;
      float w = acc[i] + b2[cbase + i];
      float ws = w * x_s[(size_t)src * NS + sji];
      float* dp = acc_v + (size_t)dst * (TPC * 3) + sji * 3;
      unsafeAtomicAdd(dp + 0, ws * r1x);
      unsafeAtomicAdd(dp + 1, ws * r1y);
      unsafeAtomicAdd(dp + 2, ws * r1z);
    }
  } else {                        // w_vs1: msg_v[:, 128+u, c] = w * v_j[u][c] * r0
    const int u0 = cbase - 320;
    #pragma unroll
    for (int i = 0; i < 8; ++i) {
      const int u = u0 + i;
      float w = (acc[i] + b2[cbase + i]) * r0;
      const float* vj = x_v + (size_t)src * (NV * 3) + u * 3;
      float* dp = acc_v + (size_t)dst * (TPC * 3) + (NS + u) * 3;
      unsafeAtomicAdd(dp + 0, w * vj[0]);
      unsafeAtomicAdd(dp + 1, w * vj[1]);
      unsafeAtomicAdd(dp + 2, w * vj[2]);
    }
  }
}

// ---------------- Kernel C: fused edge MLP + messages + atomic segment-sum
__global__ __launch_bounds__(256) void edge_kernel(
    const float* __restrict__ edge_attr, const float* __restrict__ edge_rshs,
    const int* __restrict__ edge_index,
    const float* __restrict__ W1, const float* __restrict__ b1,
    const float* __restrict__ W2, const float* __restrict__ b2,
    const float* __restrict__ x_s, const float* __restrict__ x_v,
    float* __restrict__ acc_s, float* __restrict__ acc_v) {
  __shared__ float ea_sh[EPB][NBASIS];
  __shared__ float Hs[EPB * 132];      // padded stride 132 -> conflict-free b128 reads
  __shared__ float W2s[64 * 128];      // one k-chunk (64 rows) x 128-col tile
  __shared__ int src_sh[EPB];
  __shared__ int dst_sh[EPB];
  __shared__ float rsh_sh[EPB][4];
  const int t = threadIdx.x;
  const int eblk = blockIdx.x * EPB;

  for (int i = t; i < EPB * NBASIS; i += 256)
    ea_sh[i >> 4][i & 15] = edge_attr[(size_t)eblk * NBASIS + i];
  for (int i = t; i < EPB * 4; i += 256)
    rsh_sh[i >> 2][i & 3] = edge_rshs[(size_t)eblk * 4 + i];
  if (t < EPB) {
    dst_sh[t] = edge_index[eblk + t];
    src_sh[t] = edge_index[NEDGE + eblk + t];
  }
  __syncthreads();

  // phase 1: H[e][j] = silu(ea[e] . W1[:,j] + b1[j])
  for (int p = 0; p < (EPB * HID) / 256; ++p) {
    const int idx = p * 256 + t;
    const int e = idx >> 7;
    const int j = idx & 127;
    float a = b1[j];
    #pragma unroll
    for (int k = 0; k < NBASIS; ++k) a = fmaf(ea_sh[e][k], W1[k * HID + j], a);
    Hs[e * 132 + j] = silu_f(a);
  }
  __syncthreads();

  const int ep = t & 15;
  const int cg = t >> 4;               // 16 col-groups of 8 cols
  const int e0 = ep, e1 = ep + 16;
  const int src0 = src_sh[e0], dst0 = dst_sh[e0];
  const int src1 = src_sh[e1], dst1 = dst_sh[e1];
  const float r00 = rsh_sh[e0][0], r1x0 = rsh_sh[e0][1], r1y0 = rsh_sh[e0][2], r1z0 = rsh_sh[e0][3];
  const float r01 = rsh_sh[e1][0], r1x1 = rsh_sh[e1][1], r1y1 = rsh_sh[e1][2], r1z1 = rsh_sh[e1][3];

  for (int tile = 0; tile < 3; ++tile) {
    const int c0 = tile * 128;
    float acc0[8] = {0, 0, 0, 0, 0, 0, 0, 0};
    float acc1[8] = {0, 0, 0, 0, 0, 0, 0, 0};
    for (int kc = 0; kc < 2; ++kc) {
      // stage W2[kc*64 : kc*64+64, c0 : c0+128] into LDS (float4, coalesced)
      for (int idx = t; idx < 2048; idx += 256) {
        const int r = idx >> 5, c4 = idx & 31;
        ((float4*)W2s)[(r << 5) + c4] =
            *(const float4*)(W2 + (size_t)(kc * 64 + r) * WOUT + c0 + (c4 << 2));
      }
      __syncthreads();
      const float* Hp0 = Hs + e0 * 132 + kc * 64;
      const float* Hp1 = Hs + e1 * 132 + kc * 64;
      const float* wp = W2s + cg * 8;
      #pragma unroll 2
      for (int k4 = 0; k4 < 64; k4 += 4) {
        float h0[4], h1[4];
        *(float4*)h0 = *(const float4*)(Hp0 + k4);
        *(float4*)h1 = *(const float4*)(Hp1 + k4);
        #pragma unroll
        for (int kk = 0; kk < 4; ++kk) {
          const float* wr = wp + (k4 + kk) * 128;
          float4 wa = *(const float4*)(wr);
          float4 wb = *(const float4*)(wr + 4);
          const float a0 = h0[kk], a1 = h1[kk];
          acc0[0] = fmaf(a0, wa.x, acc0[0]); acc0[1] = fmaf(a0, wa.y, acc0[1]);
          acc0[2] = fmaf(a0, wa.z, acc0[2]); acc0[3] = fmaf(a0, wa.w, acc0[3]);
          acc0[4] = fmaf(a0, wb.x, acc0[4]); acc0[5] = fmaf(a0, wb.y, acc0[5]);
          acc0[6] = fmaf(a0, wb.z, acc0[6]); acc0[7] = fmaf(a0, wb.w, acc0[7]);
          acc1[0] = fmaf(a1, wa.x, acc1[0]); acc1[1] = fmaf(a1, wa.y, acc1[1]);
          acc1[2] = fmaf(a1, wa.z, acc1[2]); acc1[3] = fmaf(a1, wa.w, acc1[3]);
          acc1[4] = fmaf(a1, wb.x, acc1[4]); acc1[5] = fmaf(a1, wb.y, acc1[5]);
          acc1[6] = fmaf(a1, wb.z, acc1[6]); acc1[7] = fmaf(a1, wb.w, acc1[7]);
        }
      }
      __syncthreads();
    }
    const int cbase = c0 + cg * 8;
    edge_epilogue(acc0, cbase, src0, dst0, r00, r1x0, r1y0, r1z0, b2, x_s, x_v, acc_s, acc_v);
    edge_epilogue(acc1, cbase, src1, dst1, r01, r1x1, r1y1, r1z1, b2, x_s, x_v, acc_s, acc_v);
  }
}

// ---------------- Kernel D: gates + post GEMMs + residual
__global__ __launch_bounds__(256) void node_post(
    const float* __restrict__ acc_s, const float* __restrict__ acc_v,
    const float* __restrict__ Wqs, const float* __restrict__ Wqv,
    const float* __restrict__ x_s, const float* __restrict__ x_v,
    float* __restrict__ out) {
  const int n = blockIdx.x;
  const int t = threadIdx.x;
  __shared__ float gs_sh[TPC];
  __shared__ float gv_sh[TPC * 3];
  const float* as = acc_s + (size_t)n * TPC;
  const float* av = acc_v + (size_t)n * TPC * 3;
  if (t < TPC) {
    gs_sh[t] = silu_f(as[t]);
    const float vx = av[t * 3 + 0], vy = av[t * 3 + 1], vz = av[t * 3 + 2];
    const float nrm = sqrtf(fmaf(vx, vx, fmaf(vy, vy, vz * vz)) + 1e-12f);
    const float sg = 1.f / (1.f + __expf(-nrm));
    gv_sh[t * 3 + 0] = vx * sg; gv_sh[t * 3 + 1] = vy * sg; gv_sh[t * 3 + 2] = vz * sg;
  }
  __syncthreads();
  float* orow = out + (size_t)n * 320;
  for (int o = t; o < 320; o += 256) {
    if (o < NS) {
      float a = 0.f;
      #pragma unroll 8
      for (int u = 0; u < TPC; ++u) a = fmaf(gs_sh[u], Wqs[u * NS + o], a);
      orow[o] = x_s[(size_t)n * NS + o] + a * 0.07216878364870323f;
    } else {
      const int q = o - NS;
      const int vch = q / 3, c = q - vch * 3;
      float a = 0.f;
      #pragma unroll 8
      for (int u = 0; u < TPC; ++u) a = fmaf(gv_sh[u * 3 + c], Wqv[u * NV + vch], a);
      orow[o] = x_v[(size_t)n * (NV * 3) + q] + a * 0.07216878364870323f;
    }
  }
}

extern "C" void kernel_launch(void* const* d_in, const int* in_sizes, int n_in,
                              void* d_out, int out_size, void* d_ws, size_t ws_size,
                              hipStream_t stream) {
  const float* node_feat = (const float*)d_in[0];
  const float* edge_attr = (const float*)d_in[1];
  const float* edge_rshs = (const float*)d_in[2];
  const int*   edge_index = (const int*)d_in[3];
  const float* Wps = (const float*)d_in[4];
  const float* bps = (const float*)d_in[5];
  const float* Wpv = (const float*)d_in[6];
  const float* W1  = (const float*)d_in[7];
  const float* b1  = (const float*)d_in[8];
  const float* W2  = (const float*)d_in[9];
  const float* b2  = (const float*)d_in[10];
  const float* Wqs = (const float*)d_in[11];
  const float* Wqv = (const float*)d_in[12];
  float* out = (float*)d_out;

  float* x_s   = (float*)d_ws;                       // 16000*128 f32
  float* x_v   = x_s   + (size_t)NNODE * NS;         // 16000*192 f32
  float* acc_s = x_v   + (size_t)NNODE * NV * 3;     // 16000*192 f32
  float* acc_v = acc_s + (size_t)NNODE * TPC;        // 16000*576 f32

  hipMemsetAsync(acc_s, 0, (size_t)NNODE * (TPC + TPC * 3) * sizeof(float), stream);
  node_pre<<<NNODE, 256, 0, stream>>>(node_feat, Wps, bps, Wpv, x_s, x_v);
  edge_kernel<<<NEDGE / EPB, 256, 0, stream>>>(edge_attr, edge_rshs, edge_index,
      W1, b1, W2, b2, x_s, x_v, acc_s, acc_v);
  node_post<<<NNODE, 256, 0, stream>>>(acc_s, acc_v, Wqs, Wqv, x_s, x_v, out);
}

// Round 2
// 914.581 us; speedup vs baseline: 10.4976x; 10.4976x over previous
//
#include <hip/hip_runtime.h>
#include <hip/hip_bf16.h>

#define NS 128
#define NV 64
#define TPC 192
#define NBASIS 16
#define HID 128
#define WOUT 384
#define NNODE 16000
#define NEDGE 256000
#define EPB 32

__device__ __forceinline__ float silu_f(float x) { return x / (1.0f + __expf(-x)); }

// ---------------- Kernel A: x_s = s@W_pre_s/sqrt(128)+b ; x_v = v@W_pre_v/sqrt(64)
__global__ __launch_bounds__(256) void node_pre(
    const float* __restrict__ node_feat, const float* __restrict__ Wps,
    const float* __restrict__ bps, const float* __restrict__ Wpv,
    float* __restrict__ x_s, float* __restrict__ x_v) {
  const int n = blockIdx.x;
  const int t = threadIdx.x;
  __shared__ float s_sh[NS];
  __shared__ float v_sh[NV * 3];
  const float* row = node_feat + (size_t)n * 320;
  for (int i = t; i < 320; i += 256) {
    float val = row[i];
    if (i < NS) s_sh[i] = val; else v_sh[i - NS] = val;
  }
  __syncthreads();
  for (int o = t; o < 320; o += 256) {
    if (o < NS) {
      float a = 0.f;
      #pragma unroll 8
      for (int u = 0; u < NS; ++u) a = fmaf(s_sh[u], Wps[u * NS + o], a);
      x_s[(size_t)n * NS + o] = a * 0.08838834764831845f + bps[o];
    } else {
      const int q = o - NS;
      const int vch = q / 3, c = q - vch * 3;
      float a = 0.f;
      #pragma unroll 8
      for (int u = 0; u < NV; ++u) a = fmaf(v_sh[u * 3 + c], Wpv[u * NV + vch], a);
      x_v[(size_t)n * (NV * 3) + q] = a * 0.125f;
    }
  }
}

// ================= CSR build =================
__global__ void hist_kernel(const int* __restrict__ ei, int* __restrict__ cnt) {
  int e = blockIdx.x * 256 + threadIdx.x;
  if (e < NEDGE) atomicAdd(&cnt[ei[e]], 1);
}

__global__ __launch_bounds__(256) void scan_kernel(
    const int* __restrict__ cnt, int* __restrict__ row_start, int* __restrict__ cursor) {
  __shared__ int part[256];
  const int t = threadIdx.x;
  const int base = t * 63;
  int s = 0;
  for (int i = 0; i < 63; ++i) {
    int idx = base + i;
    if (idx < NNODE) s += cnt[idx];
  }
  part[t] = s;
  __syncthreads();
  if (t == 0) {
    int run = 0;
    for (int i = 0; i < 256; ++i) { int x = part[i]; part[i] = run; run += x; }
  }
  __syncthreads();
  int run = part[t];
  for (int i = 0; i < 63; ++i) {
    int idx = base + i;
    if (idx < NNODE) {
      int c = cnt[idx];
      row_start[idx] = run;
      cursor[idx] = run;
      run += c;
    }
  }
  if (t == 255) row_start[NNODE] = run;
}

__global__ void scatter_kernel(const int* __restrict__ ei, int* __restrict__ cursor,
                               int* __restrict__ eid) {
  int e = blockIdx.x * 256 + threadIdx.x;
  if (e < NEDGE) {
    int p = atomicAdd(&cursor[ei[e]], 1);
    eid[p] = e;
  }
}

// ================= Phase A: edge MLP -> compact bf16 messages =================
// layout per edge (384 bf16): [0:192)=msg_s (fully multiplied)
//                             [192:320)=w_sv1*s_j   [320:384)=w_vs1*r0
__device__ __forceinline__ void store_msg(
    const float* __restrict__ acc, int cbase, int src,
    float r0, float r1x, float r1y, float r1z,
    const float* __restrict__ b2, const float* __restrict__ x_s,
    const float* __restrict__ x_v, __hip_bfloat16* __restrict__ m) {
  __hip_bfloat16 tmp[8];
  if (cbase < 128) {
    const float* sj = x_s + (size_t)src * NS + cbase;
    #pragma unroll
    for (int i = 0; i < 8; ++i)
      tmp[i] = __float2bfloat16((acc[i] + b2[cbase + i]) * sj[i] * r0);
  } else if (cbase < 192) {
    const int u0 = cbase - 128;
    #pragma unroll
    for (int i = 0; i < 8; ++i) {
      const float* vj = x_v + (size_t)src * (NV * 3) + (u0 + i) * 3;
      float vd = vj[0] * r1x + vj[1] * r1y + vj[2] * r1z;
      tmp[i] = __float2bfloat16((acc[i] + b2[cbase + i]) * vd * 0.5773502691896258f);
    }
  } else if (cbase < 320) {
    const float* sj = x_s + (size_t)src * NS + (cbase - 192);
    #pragma unroll
    for (int i = 0; i < 8; ++i)
      tmp[i] = __float2bfloat16((acc[i] + b2[cbase + i]) * sj[i]);
  } else {
    #pragma unroll
    for (int i = 0; i < 8; ++i)
      tmp[i] = __float2bfloat16((acc[i] + b2[cbase + i]) * r0);
  }
  *reinterpret_cast<int4*>(m + cbase) = *reinterpret_cast<const int4*>(tmp);
}

__global__ __launch_bounds__(256) void edge_mlp(
    const float* __restrict__ edge_attr, const float* __restrict__ edge_rshs,
    const int* __restrict__ edge_index,
    const float* __restrict__ W1, const float* __restrict__ b1,
    const float* __restrict__ W2, const float* __restrict__ b2,
    const float* __restrict__ x_s, const float* __restrict__ x_v,
    __hip_bfloat16* __restrict__ msg) {
  __shared__ float ea_sh[EPB][NBASIS];
  __shared__ float Hs[EPB * 132];
  __shared__ float W2s[64 * 128];
  __shared__ int src_sh[EPB];
  __shared__ float rsh_sh[EPB][4];
  const int t = threadIdx.x;
  const int eblk = blockIdx.x * EPB;

  for (int i = t; i < EPB * NBASIS; i += 256)
    ea_sh[i >> 4][i & 15] = edge_attr[(size_t)eblk * NBASIS + i];
  for (int i = t; i < EPB * 4; i += 256)
    rsh_sh[i >> 2][i & 3] = edge_rshs[(size_t)eblk * 4 + i];
  if (t < EPB) src_sh[t] = edge_index[NEDGE + eblk + t];
  __syncthreads();

  for (int p = 0; p < (EPB * HID) / 256; ++p) {
    const int idx = p * 256 + t;
    const int e = idx >> 7;
    const int j = idx & 127;
    float a = b1[j];
    #pragma unroll
    for (int k = 0; k < NBASIS; ++k) a = fmaf(ea_sh[e][k], W1[k * HID + j], a);
    Hs[e * 132 + j] = silu_f(a);
  }
  __syncthreads();

  const int ep = t & 15;
  const int cg = t >> 4;
  const int e0 = ep, e1 = ep + 16;
  const int src0 = src_sh[e0], src1 = src_sh[e1];
  const float r00 = rsh_sh[e0][0], r1x0 = rsh_sh[e0][1], r1y0 = rsh_sh[e0][2], r1z0 = rsh_sh[e0][3];
  const float r01 = rsh_sh[e1][0], r1x1 = rsh_sh[e1][1], r1y1 = rsh_sh[e1][2], r1z1 = rsh_sh[e1][3];
  __hip_bfloat16* m0 = msg + (size_t)(eblk + e0) * 384;
  __hip_bfloat16* m1 = msg + (size_t)(eblk + e1) * 384;

  for (int tile = 0; tile < 3; ++tile) {
    const int c0 = tile * 128;
    float acc0[8] = {0, 0, 0, 0, 0, 0, 0, 0};
    float acc1[8] = {0, 0, 0, 0, 0, 0, 0, 0};
    for (int kc = 0; kc < 2; ++kc) {
      for (int idx = t; idx < 2048; idx += 256) {
        const int r = idx >> 5, c4 = idx & 31;
        ((float4*)W2s)[(r << 5) + c4] =
            *(const float4*)(W2 + (size_t)(kc * 64 + r) * WOUT + c0 + (c4 << 2));
      }
      __syncthreads();
      const float* Hp0 = Hs + e0 * 132 + kc * 64;
      const float* Hp1 = Hs + e1 * 132 + kc * 64;
      const float* wp = W2s + cg * 8;
      #pragma unroll 2
      for (int k4 = 0; k4 < 64; k4 += 4) {
        float h0[4], h1[4];
        *(float4*)h0 = *(const float4*)(Hp0 + k4);
        *(float4*)h1 = *(const float4*)(Hp1 + k4);
        #pragma unroll
        for (int kk = 0; kk < 4; ++kk) {
          const float* wr = wp + (k4 + kk) * 128;
          float4 wa = *(const float4*)(wr);
          float4 wb = *(const float4*)(wr + 4);
          const float a0 = h0[kk], a1 = h1[kk];
          acc0[0] = fmaf(a0, wa.x, acc0[0]); acc0[1] = fmaf(a0, wa.y, acc0[1]);
          acc0[2] = fmaf(a0, wa.z, acc0[2]); acc0[3] = fmaf(a0, wa.w, acc0[3]);
          acc0[4] = fmaf(a0, wb.x, acc0[4]); acc0[5] = fmaf(a0, wb.y, acc0[5]);
          acc0[6] = fmaf(a0, wb.z, acc0[6]); acc0[7] = fmaf(a0, wb.w, acc0[7]);
          acc1[0] = fmaf(a1, wa.x, acc1[0]); acc1[1] = fmaf(a1, wa.y, acc1[1]);
          acc1[2] = fmaf(a1, wa.z, acc1[2]); acc1[3] = fmaf(a1, wa.w, acc1[3]);
          acc1[4] = fmaf(a1, wb.x, acc1[4]); acc1[5] = fmaf(a1, wb.y, acc1[5]);
          acc1[6] = fmaf(a1, wb.z, acc1[6]); acc1[7] = fmaf(a1, wb.w, acc1[7]);
        }
      }
      __syncthreads();
    }
    const int cbase = c0 + cg * 8;
    store_msg(acc0, cbase, src0, r00, r1x0, r1y0, r1z0, b2, x_s, x_v, m0);
    store_msg(acc1, cbase, src1, r01, r1x1, r1y1, r1z1, b2, x_s, x_v, m1);
  }
}

// ================= Phase B: per-node gather + gates + post GEMMs + residual =====
__global__ __launch_bounds__(256) void node_gather_post(
    const __hip_bfloat16* __restrict__ msg, const int* __restrict__ row_start,
    const int* __restrict__ eid, const int* __restrict__ edge_index,
    const float* __restrict__ edge_rshs, const float* __restrict__ x_s,
    const float* __restrict__ x_v, const float* __restrict__ Wqs,
    const float* __restrict__ Wqv, float* __restrict__ out) {
  const int n = blockIdx.x;
  const int t = threadIdx.x;
  const int beg = row_start[n], end = row_start[n + 1];

  // per-channel precompute: channels t, t+256, t+512
  int kind[3], moff[3], col_[3], voff[3];
  #pragma unroll
  for (int j = 0; j < 3; ++j) {
    const int c = t + 256 * j;
    if (c < 192) { kind[j] = 0; moff[j] = c; col_[j] = 0; voff[j] = 0; }
    else {
      const int q = c - 192;
      const int row = q / 3, col = q - row * 3;
      col_[j] = col;
      if (row < 128) { kind[j] = 1; moff[j] = 192 + row; voff[j] = 0; }
      else { kind[j] = 2; moff[j] = 320 + (row - 128); voff[j] = (row - 128) * 3 + col; }
    }
  }

  float a0 = 0.f, a1 = 0.f, a2 = 0.f;
  for (int i = beg; i < end; ++i) {
    const int e = eid[i];
    const __hip_bfloat16* m = msg + (size_t)e * 384;
    const int src = edge_index[NEDGE + e];
    const float* xvs = x_v + (size_t)src * (NV * 3);
    float r1[3];
    r1[0] = edge_rshs[e * 4 + 1]; r1[1] = edge_rshs[e * 4 + 2]; r1[2] = edge_rshs[e * 4 + 3];
    {
      float mv = __bfloat162float(m[moff[0]]);
      a0 += (kind[0] == 0) ? mv : (kind[0] == 1 ? mv * r1[col_[0]] : mv * xvs[voff[0]]);
    }
    {
      float mv = __bfloat162float(m[moff[1]]);
      a1 += (kind[1] == 0) ? mv : (kind[1] == 1 ? mv * r1[col_[1]] : mv * xvs[voff[1]]);
    }
    {
      float mv = __bfloat162float(m[moff[2]]);
      a2 += (kind[2] == 0) ? mv : (kind[2] == 1 ? mv * r1[col_[2]] : mv * xvs[voff[2]]);
    }
  }

  __shared__ float accsh[768];
  __shared__ float gs[192];
  __shared__ float gv[576];
  accsh[t] = a0; accsh[t + 256] = a1; accsh[t + 512] = a2;
  __syncthreads();
  if (t < 192) {
    gs[t] = silu_f(accsh[t]);
    const float vx = accsh[192 + 3 * t], vy = accsh[192 + 3 * t + 1], vz = accsh[192 + 3 * t + 2];
    const float nrm = sqrtf(fmaf(vx, vx, fmaf(vy, vy, vz * vz)) + 1e-12f);
    const float sg = 1.f / (1.f + __expf(-nrm));
    gv[3 * t] = vx * sg; gv[3 * t + 1] = vy * sg; gv[3 * t + 2] = vz * sg;
  }
  __syncthreads();

  float* orow = out + (size_t)n * 320;
  for (int o = t; o < 320; o += 256) {
    float a = 0.f;
    if (o < NS) {
      #pragma unroll 8
      for (int u = 0; u < TPC; ++u) a = fmaf(gs[u], Wqs[u * NS + o], a);
      orow[o] = x_s[(size_t)n * NS + o] + a * 0.07216878364870323f;
    } else {
      const int q = o - NS;
      const int vch = q / 3, c = q - vch * 3;
      #pragma unroll 8
      for (int u = 0; u < TPC; ++u) a = fmaf(gv[u * 3 + c], Wqv[u * NV + vch], a);
      orow[o] = x_v[(size_t)n * (NV * 3) + q] + a * 0.07216878364870323f;
    }
  }
}

// ================= Fallback (old atomic path) =================
__device__ __forceinline__ void edge_epilogue(
    const float* __restrict__ acc, int cbase, int src, int dst,
    float r0, float r1x, float r1y, float r1z,
    const float* __restrict__ b2, const float* __restrict__ x_s,
    const float* __restrict__ x_v, float* __restrict__ acc_s,
    float* __restrict__ acc_v) {
  if (cbase < 128) {
    const float* sj = x_s + (size_t)src * NS + cbase;
    float* ap = acc_s + (size_t)dst * TPC + cbase;
    #pragma unroll
    for (int i = 0; i < 8; ++i) {
      float w = acc[i] + b2[cbase + i];
      unsafeAtomicAdd(ap + i, w * sj[i] * r0);
    }
  } else if (cbase < 192) {
    const int u0 = cbase - 128;
    #pragma unroll
    for (int i = 0; i < 8; ++i) {
      const int u = u0 + i;
      const float* vj = x_v + (size_t)src * (NV * 3) + u * 3;
      float vd = vj[0] * r1x + vj[1] * r1y + vj[2] * r1z;
      float w = acc[i] + b2[cbase + i];
      unsafeAtomicAdd(acc_s + (size_t)dst * TPC + NS + u, w * vd * 0.5773502691896258f);
    }
  } else if (cbase < 320) {
    const int s0 = cbase - 192;
    #pragma unroll
    for (int i = 0; i < 8; ++i) {
      const int sji = s0 + i;
      float w = acc[i] + b2[cbase + i];
      float ws = w * x_s[(size_t)src * NS + sji];
      float* dp = acc_v + (size_t)dst * (TPC * 3) + sji * 3;
      unsafeAtomicAdd(dp + 0, ws * r1x);
      unsafeAtomicAdd(dp + 1, ws * r1y);
      unsafeAtomicAdd(dp + 2, ws * r1z);
    }
  } else {
    const int u0 = cbase - 320;
    #pragma unroll
    for (int i = 0; i < 8; ++i) {
      const int u = u0 + i;
      float w = (acc[i] + b2[cbase + i]) * r0;
      const float* vj = x_v + (size_t)src * (NV * 3) + u * 3;
      float* dp = acc_v + (size_t)dst * (TPC * 3) + (NS + u) * 3;
      unsafeAtomicAdd(dp + 0, w * vj[0]);
      unsafeAtomicAdd(dp + 1, w * vj[1]);
      unsafeAtomicAdd(dp + 2, w * vj[2]);
    }
  }
}

__global__ __launch_bounds__(256) void edge_kernel(
    const float* __restrict__ edge_attr, const float* __restrict__ edge_rshs,
    const int* __restrict__ edge_index,
    const float* __restrict__ W1, const float* __restrict__ b1,
    const float* __restrict__ W2, const float* __restrict__ b2,
    const float* __restrict__ x_s, const float* __restrict__ x_v,
    float* __restrict__ acc_s, float* __restrict__ acc_v) {
  __shared__ float ea_sh[EPB][NBASIS];
  __shared__ float Hs[EPB * 132];
  __shared__ float W2s[64 * 128];
  __shared__ int src_sh[EPB];
  __shared__ int dst_sh[EPB];
  __shared__ float rsh_sh[EPB][4];
  const int t = threadIdx.x;
  const int eblk = blockIdx.x * EPB;

  for (int i = t; i < EPB * NBASIS; i += 256)
    ea_sh[i >> 4][i & 15] = edge_attr[(size_t)eblk * NBASIS + i];
  for (int i = t; i < EPB * 4; i += 256)
    rsh_sh[i >> 2][i & 3] = edge_rshs[(size_t)eblk * 4 + i];
  if (t < EPB) {
    dst_sh[t] = edge_index[eblk + t];
    src_sh[t] = edge_index[NEDGE + eblk + t];
  }
  __syncthreads();

  for (int p = 0; p < (EPB * HID) / 256; ++p) {
    const int idx = p * 256 + t;
    const int e = idx >> 7;
    const int j = idx & 127;
    float a = b1[j];
    #pragma unroll
    for (int k = 0; k < NBASIS; ++k) a = fmaf(ea_sh[e][k], W1[k * HID + j], a);
    Hs[e * 132 + j] = silu_f(a);
  }
  __syncthreads();

  const int ep = t & 15;
  const int cg = t >> 4;
  const int e0 = ep, e1 = ep + 16;
  const int src0 = src_sh[e0], dst0 = dst_sh[e0];
  const int src1 = src_sh[e1], dst1 = dst_sh[e1];
  const float r00 = rsh_sh[e0][0], r1x0 = rsh_sh[e0][1], r1y0 = rsh_sh[e0][2], r1z0 = rsh_sh[e0][3];
  const float r01 = rsh_sh[e1][0], r1x1 = rsh_sh[e1][1], r1y1 = rsh_sh[e1][2], r1z1 = rsh_sh[e1][3];

  for (int tile = 0; tile < 3; ++tile) {
    const int c0 = tile * 128;
    float acc0[8] = {0, 0, 0, 0, 0, 0, 0, 0};
    float acc1[8] = {0, 0, 0, 0, 0, 0, 0, 0};
    for (int kc = 0; kc < 2; ++kc) {
      for (int idx = t; idx < 2048; idx += 256) {
        const int r = idx >> 5, c4 = idx & 31;
        ((float4*)W2s)[(r << 5) + c4] =
            *(const float4*)(W2 + (size_t)(kc * 64 + r) * WOUT + c0 + (c4 << 2));
      }
      __syncthreads();
      const float* Hp0 = Hs + e0 * 132 + kc * 64;
      const float* Hp1 = Hs + e1 * 132 + kc * 64;
      const float* wp = W2s + cg * 8;
      #pragma unroll 2
      for (int k4 = 0; k4 < 64; k4 += 4) {
        float h0[4], h1[4];
        *(float4*)h0 = *(const float4*)(Hp0 + k4);
        *(float4*)h1 = *(const float4*)(Hp1 + k4);
        #pragma unroll
        for (int kk = 0; kk < 4; ++kk) {
          const float* wr = wp + (k4 + kk) * 128;
          float4 wa = *(const float4*)(wr);
          float4 wb = *(const float4*)(wr + 4);
          const float a0 = h0[kk], a1 = h1[kk];
          acc0[0] = fmaf(a0, wa.x, acc0[0]); acc0[1] = fmaf(a0, wa.y, acc0[1]);
          acc0[2] = fmaf(a0, wa.z, acc0[2]); acc0[3] = fmaf(a0, wa.w, acc0[3]);
          acc0[4] = fmaf(a0, wb.x, acc0[4]); acc0[5] = fmaf(a0, wb.y, acc0[5]);
          acc0[6] = fmaf(a0, wb.z, acc0[6]); acc0[7] = fmaf(a0, wb.w, acc0[7]);
          acc1[0] = fmaf(a1, wa.x, acc1[0]); acc1[1] = fmaf(a1, wa.y, acc1[1]);
          acc1[2] = fmaf(a1, wa.z, acc1[2]); acc1[3] = fmaf(a1, wa.w, acc1[3]);
          acc1[4] = fmaf(a1, wb.x, acc1[4]); acc1[5] = fmaf(a1, wb.y, acc1[5]);
          acc1[6] = fmaf(a1, wb.z, acc1[6]); acc1[7] = fmaf(a1, wb.w, acc1[7]);
        }
      }
      __syncthreads();
    }
    const int cbase = c0 + cg * 8;
    edge_epilogue(acc0, cbase, src0, dst0, r00, r1x0, r1y0, r1z0, b2, x_s, x_v, acc_s, acc_v);
    edge_epilogue(acc1, cbase, src1, dst1, r01, r1x1, r1y1, r1z1, b2, x_s, x_v, acc_s, acc_v);
  }
}

__global__ __launch_bounds__(256) void node_post(
    const float* __restrict__ acc_s, const float* __restrict__ acc_v,
    const float* __restrict__ Wqs, const float* __restrict__ Wqv,
    const float* __restrict__ x_s, const float* __restrict__ x_v,
    float* __restrict__ out) {
  const int n = blockIdx.x;
  const int t = threadIdx.x;
  __shared__ float gs_sh[TPC];
  __shared__ float gv_sh[TPC * 3];
  const float* as = acc_s + (size_t)n * TPC;
  const float* av = acc_v + (size_t)n * TPC * 3;
  if (t < TPC) {
    gs_sh[t] = silu_f(as[t]);
    const float vx = av[t * 3 + 0], vy = av[t * 3 + 1], vz = av[t * 3 + 2];
    const float nrm = sqrtf(fmaf(vx, vx, fmaf(vy, vy, vz * vz)) + 1e-12f);
    const float sg = 1.f / (1.f + __expf(-nrm));
    gv_sh[t * 3 + 0] = vx * sg; gv_sh[t * 3 + 1] = vy * sg; gv_sh[t * 3 + 2] = vz * sg;
  }
  __syncthreads();
  float* orow = out + (size_t)n * 320;
  for (int o = t; o < 320; o += 256) {
    if (o < NS) {
      float a = 0.f;
      #pragma unroll 8
      for (int u = 0; u < TPC; ++u) a = fmaf(gs_sh[u], Wqs[u * NS + o], a);
      orow[o] = x_s[(size_t)n * NS + o] + a * 0.07216878364870323f;
    } else {
      const int q = o - NS;
      const int vch = q / 3, c = q - vch * 3;
      float a = 0.f;
      #pragma unroll 8
      for (int u = 0; u < TPC; ++u) a = fmaf(gv_sh[u * 3 + c], Wqv[u * NV + vch], a);
      orow[o] = x_v[(size_t)n * (NV * 3) + q] + a * 0.07216878364870323f;
    }
  }
}

extern "C" void kernel_launch(void* const* d_in, const int* in_sizes, int n_in,
                              void* d_out, int out_size, void* d_ws, size_t ws_size,
                              hipStream_t stream) {
  const float* node_feat = (const float*)d_in[0];
  const float* edge_attr = (const float*)d_in[1];
  const float* edge_rshs = (const float*)d_in[2];
  const int*   edge_index = (const int*)d_in[3];
  const float* Wps = (const float*)d_in[4];
  const float* bps = (const float*)d_in[5];
  const float* Wpv = (const float*)d_in[6];
  const float* W1  = (const float*)d_in[7];
  const float* b1  = (const float*)d_in[8];
  const float* W2  = (const float*)d_in[9];
  const float* b2  = (const float*)d_in[10];
  const float* Wqs = (const float*)d_in[11];
  const float* Wqv = (const float*)d_in[12];
  float* out = (float*)d_out;

  // new-path workspace layout
  const size_t xs_elems  = (size_t)NNODE * NS;          // f32
  const size_t xv_elems  = (size_t)NNODE * NV * 3;      // f32
  const size_t msg_elems = (size_t)NEDGE * 384;         // bf16
  size_t need = (xs_elems + xv_elems) * 4 + msg_elems * 2 +
                (NNODE + 1) * 4 + NNODE * 4 + (size_t)NEDGE * 4 + 64;

  if (ws_size >= need) {
    float* x_s = (float*)d_ws;
    float* x_v = x_s + xs_elems;
    __hip_bfloat16* msg = (__hip_bfloat16*)(x_v + xv_elems);
    int* row_start = (int*)(msg + msg_elems);
    int* cursor = row_start + (NNODE + 1);
    int* eid = cursor + NNODE;

    hipMemsetAsync(cursor, 0, NNODE * sizeof(int), stream);
    node_pre<<<NNODE, 256, 0, stream>>>(node_feat, Wps, bps, Wpv, x_s, x_v);
    hist_kernel<<<(NEDGE + 255) / 256, 256, 0, stream>>>(edge_index, cursor);
    scan_kernel<<<1, 256, 0, stream>>>(cursor, row_start, cursor);
    scatter_kernel<<<(NEDGE + 255) / 256, 256, 0, stream>>>(edge_index, cursor, eid);
    edge_mlp<<<NEDGE / EPB, 256, 0, stream>>>(edge_attr, edge_rshs, edge_index,
        W1, b1, W2, b2, x_s, x_v, msg);
    node_gather_post<<<NNODE, 256, 0, stream>>>(msg, row_start, eid, edge_index,
        edge_rshs, x_s, x_v, Wqs, Wqv, out);
  } else {
    // fallback: old atomic path
    float* x_s   = (float*)d_ws;
    float* x_v   = x_s   + xs_elems;
    float* acc_s = x_v   + xv_elems;
    float* acc_v = acc_s + (size_t)NNODE * TPC;

    hipMemsetAsync(acc_s, 0, (size_t)NNODE * (TPC + TPC * 3) * sizeof(float), stream);
    node_pre<<<NNODE, 256, 0, stream>>>(node_feat, Wps, bps, Wpv, x_s, x_v);
    edge_kernel<<<NEDGE / EPB, 256, 0, stream>>>(edge_attr, edge_rshs, edge_index,
        W1, b1, W2, b2, x_s, x_v, acc_s, acc_v);
    node_post<<<NNODE, 256, 0, stream>>>(acc_s, acc_v, Wqs, Wqv, x_s, x_v, out);
  }
}

// Round 3
// 637.764 us; speedup vs baseline: 15.0541x; 1.4340x over previous
//
#include <hip/hip_runtime.h>
#include <hip/hip_bf16.h>

#define NS 128
#define NV 64
#define TPC 192
#define NBASIS 16
#define HID 128
#define WOUT 384
#define NNODE 16000
#define NEDGE 256000
#define EPB 32

typedef __attribute__((ext_vector_type(8))) short bf16x8;
typedef __attribute__((ext_vector_type(4))) float f32x4;

__device__ __forceinline__ float silu_f(float x) { return x / (1.0f + __expf(-x)); }
__device__ __forceinline__ unsigned short bf16b(float x) {
  __hip_bfloat16 h = __float2bfloat16(x);
  return *reinterpret_cast<unsigned short*>(&h);
}

// ---------------- pack W1/W2 into MFMA B-fragment order (bf16) ----------------
// W2P[nt][k][lane][j] = bf16(W2[k*32 + (lane>>4)*8 + j][nt*16 + (lane&15)])
// W1P[nt][lane][j]    = bf16(W1[(lane>>4)*8 + j][nt*16 + (lane&15)]), 0 for k>=16
__global__ __launch_bounds__(256) void pack_weights(
    const float* __restrict__ W1, const float* __restrict__ W2,
    unsigned short* __restrict__ W1P, unsigned short* __restrict__ W2P) {
  const int id = blockIdx.x * 256 + threadIdx.x;
  if (id < 24 * 4 * 64 * 8) {
    const int j = id & 7, lane = (id >> 3) & 63, k = (id >> 9) & 3, nt = id >> 11;
    const int krow = k * 32 + (lane >> 4) * 8 + j;
    const int ncol = nt * 16 + (lane & 15);
    W2P[id] = bf16b(W2[krow * WOUT + ncol]);
  }
  if (id < 8 * 64 * 8) {
    const int j = id & 7, lane = (id >> 3) & 63, nt = id >> 9;
    const int krow = (lane >> 4) * 8 + j;
    const int ncol = nt * 16 + (lane & 15);
    W1P[id] = (krow < NBASIS) ? bf16b(W1[krow * HID + ncol]) : (unsigned short)0;
  }
}

// ---------------- node_pre: 4 nodes/block (4 FMA per weight load) ----------------
__global__ __launch_bounds__(256) void node_pre4(
    const float* __restrict__ node_feat, const float* __restrict__ Wps,
    const float* __restrict__ bps, const float* __restrict__ Wpv,
    float* __restrict__ x_s, float* __restrict__ x_v) {
  const int n0 = blockIdx.x * 4;
  const int t = threadIdx.x;
  __shared__ float s_sh[4][NS];
  __shared__ float v_sh[4][NV * 3];
  for (int i = t; i < 4 * 320; i += 256) {
    const int nn = i / 320, off = i - nn * 320;
    const float val = node_feat[(size_t)(n0 + nn) * 320 + off];
    if (off < NS) s_sh[nn][off] = val; else v_sh[nn][off - NS] = val;
  }
  __syncthreads();
  for (int o = t; o < 320; o += 256) {
    if (o < NS) {
      float a0 = 0.f, a1 = 0.f, a2 = 0.f, a3 = 0.f;
      #pragma unroll 8
      for (int u = 0; u < NS; ++u) {
        const float wv = Wps[u * NS + o];
        a0 = fmaf(s_sh[0][u], wv, a0); a1 = fmaf(s_sh[1][u], wv, a1);
        a2 = fmaf(s_sh[2][u], wv, a2); a3 = fmaf(s_sh[3][u], wv, a3);
      }
      const float b = bps[o];
      x_s[(size_t)(n0 + 0) * NS + o] = a0 * 0.08838834764831845f + b;
      x_s[(size_t)(n0 + 1) * NS + o] = a1 * 0.08838834764831845f + b;
      x_s[(size_t)(n0 + 2) * NS + o] = a2 * 0.08838834764831845f + b;
      x_s[(size_t)(n0 + 3) * NS + o] = a3 * 0.08838834764831845f + b;
    } else {
      const int q = o - NS;
      const int vch = q / 3, c = q - vch * 3;
      float a0 = 0.f, a1 = 0.f, a2 = 0.f, a3 = 0.f;
      #pragma unroll 8
      for (int u = 0; u < NV; ++u) {
        const float wv = Wpv[u * NV + vch];
        a0 = fmaf(v_sh[0][u * 3 + c], wv, a0); a1 = fmaf(v_sh[1][u * 3 + c], wv, a1);
        a2 = fmaf(v_sh[2][u * 3 + c], wv, a2); a3 = fmaf(v_sh[3][u * 3 + c], wv, a3);
      }
      x_v[(size_t)(n0 + 0) * (NV * 3) + q] = a0 * 0.125f;
      x_v[(size_t)(n0 + 1) * (NV * 3) + q] = a1 * 0.125f;
      x_v[(size_t)(n0 + 2) * (NV * 3) + q] = a2 * 0.125f;
      x_v[(size_t)(n0 + 3) * (NV * 3) + q] = a3 * 0.125f;
    }
  }
}

// ================= CSR build =================
__global__ void hist_kernel(const int* __restrict__ ei, int* __restrict__ cnt) {
  int e = blockIdx.x * 256 + threadIdx.x;
  if (e < NEDGE) atomicAdd(&cnt[ei[e]], 1);
}

__global__ __launch_bounds__(256) void scan_kernel(
    const int* __restrict__ cnt, int* __restrict__ row_start, int* __restrict__ cursor) {
  __shared__ int part[256];
  const int t = threadIdx.x;
  const int base = t * 63;
  int s = 0;
  for (int i = 0; i < 63; ++i) {
    int idx = base + i;
    if (idx < NNODE) s += cnt[idx];
  }
  part[t] = s;
  __syncthreads();
  if (t == 0) {
    int run = 0;
    for (int i = 0; i < 256; ++i) { int x = part[i]; part[i] = run; run += x; }
  }
  __syncthreads();
  int run = part[t];
  for (int i = 0; i < 63; ++i) {
    int idx = base + i;
    if (idx < NNODE) {
      int c = cnt[idx];   // read before overwrite (cnt aliases cursor)
      row_start[idx] = run;
      cursor[idx] = run;
      run += c;
    }
  }
  if (t == 255) row_start[NNODE] = run;
}

__global__ void scatter_kernel(const int* __restrict__ ei, int* __restrict__ cursor,
                               int* __restrict__ eid) {
  int e = blockIdx.x * 256 + threadIdx.x;
  if (e < NEDGE) {
    int p = atomicAdd(&cursor[ei[e]], 1);
    eid[p] = e;
  }
}

// ================= edge MLP via MFMA -> compact bf16 messages =================
// msg layout per edge (384 bf16): [0:192)=msg_s  [192:320)=w_sv1*s_j  [320:384)=w_vs1*r0
__global__ __launch_bounds__(256) void edge_mlp_mfma(
    const float* __restrict__ edge_attr, const float* __restrict__ edge_rshs,
    const int* __restrict__ edge_index,
    const unsigned short* __restrict__ W1P, const float* __restrict__ b1,
    const unsigned short* __restrict__ W2P, const float* __restrict__ b2,
    const float* __restrict__ x_s, const float* __restrict__ x_v,
    unsigned short* __restrict__ msg) {
  __shared__ __align__(16) unsigned short ea_lds[32 * 48];  // [edge][k pad48], 0 for k>=16
  __shared__ __align__(16) unsigned short Hs[32 * 136];     // [edge][hid pad136]
  __shared__ int src_sh[32];
  __shared__ float rsh_sh[32][4];
  const int t = threadIdx.x;
  const int lane = t & 63;
  const int w = t >> 6;
  const int l15 = lane & 15;
  const int l4 = lane >> 4;
  const int eblk = blockIdx.x * EPB;

  for (int i = t; i < 32 * 48; i += 256) {
    const int e = i / 48, k = i - e * 48;
    ea_lds[i] = (k < NBASIS) ? bf16b(edge_attr[(size_t)(eblk + e) * NBASIS + k])
                             : (unsigned short)0;
  }
  if (t < 32 * 4) rsh_sh[t >> 2][t & 3] = edge_rshs[(size_t)eblk * 4 + t];
  if (t < 32) src_sh[t] = edge_index[NEDGE + eblk + t];
  __syncthreads();

  // ---- GEMM1: H = silu(ea @ W1 + b1). wave w -> mtile w&1, col-half w>>1
  {
    const int mt = w & 1, ch = w >> 1;
    const bf16x8 afrag = *(const bf16x8*)&ea_lds[(mt * 16 + l15) * 48 + l4 * 8];
    #pragma unroll
    for (int nt = 0; nt < 4; ++nt) {
      const int ntg = ch * 4 + nt;
      const bf16x8 bfrag = *(const bf16x8*)&W1P[((size_t)ntg * 64 + lane) * 8];
      f32x4 d = {0.f, 0.f, 0.f, 0.f};
      d = __builtin_amdgcn_mfma_f32_16x16x32_bf16(afrag, bfrag, d, 0, 0, 0);
      const int col = ntg * 16 + l15;
      const float bias = b1[col];
      #pragma unroll
      for (int i = 0; i < 4; ++i) {
        const int e = mt * 16 + l4 * 4 + i;
        Hs[e * 136 + col] = bf16b(silu_f(d[i] + bias));
      }
    }
  }
  __syncthreads();

  // ---- preload A-frags (both mtiles, 4 k-chunks) + per-lane edge metadata
  bf16x8 afr[2][4];
  #pragma unroll
  for (int mt = 0; mt < 2; ++mt)
    #pragma unroll
    for (int k = 0; k < 4; ++k)
      afr[mt][k] = *(const bf16x8*)&Hs[(mt * 16 + l15) * 136 + k * 32 + l4 * 8];

  int srcs[2][4];
  float r0a[2][4], r1xa[2][4], r1ya[2][4], r1za[2][4];
  #pragma unroll
  for (int mt = 0; mt < 2; ++mt)
    #pragma unroll
    for (int i = 0; i < 4; ++i) {
      const int e = mt * 16 + l4 * 4 + i;
      srcs[mt][i] = src_sh[e];
      r0a[mt][i] = rsh_sh[e][0];
      r1xa[mt][i] = rsh_sh[e][1];
      r1ya[mt][i] = rsh_sh[e][2];
      r1za[mt][i] = rsh_sh[e][3];
    }

  // ---- GEMM2 + epilogue: wave w owns ntiles [w*6, w*6+6)
  for (int nn = 0; nn < 6; ++nn) {
    const int nt = w * 6 + nn;
    bf16x8 bfr[4];
    #pragma unroll
    for (int k = 0; k < 4; ++k)
      bfr[k] = *(const bf16x8*)&W2P[(((size_t)nt * 4 + k) * 64 + lane) * 8];
    f32x4 acc0 = {0.f, 0.f, 0.f, 0.f}, acc1 = {0.f, 0.f, 0.f, 0.f};
    #pragma unroll
    for (int k = 0; k < 4; ++k) {
      acc0 = __builtin_amdgcn_mfma_f32_16x16x32_bf16(afr[0][k], bfr[k], acc0, 0, 0, 0);
      acc1 = __builtin_amdgcn_mfma_f32_16x16x32_bf16(afr[1][k], bfr[k], acc1, 0, 0, 0);
    }
    const int col = nt * 16 + l15;
    const float bias = b2[col];
    if (col < NS) {                       // w_ss0 * s_j * r0
      #pragma unroll
      for (int mt = 0; mt < 2; ++mt)
        #pragma unroll
        for (int i = 0; i < 4; ++i) {
          const float wv = (mt ? acc1[i] : acc0[i]) + bias;
          const float val = wv * x_s[(size_t)srcs[mt][i] * NS + col] * r0a[mt][i];
          msg[(size_t)(eblk + mt * 16 + l4 * 4 + i) * 384 + col] = bf16b(val);
        }
    } else if (col < NS + NV) {           // w_vv0 * <v_j, r1> / sqrt3
      const int u = col - NS;
      #pragma unroll
      for (int mt = 0; mt < 2; ++mt)
        #pragma unroll
        for (int i = 0; i < 4; ++i) {
          const float wv = (mt ? acc1[i] : acc0[i]) + bias;
          const float* vj = x_v + (size_t)srcs[mt][i] * (NV * 3) + u * 3;
          const float vd = vj[0] * r1xa[mt][i] + vj[1] * r1ya[mt][i] + vj[2] * r1za[mt][i];
          const float val = wv * vd * 0.5773502691896258f;
          msg[(size_t)(eblk + mt * 16 + l4 * 4 + i) * 384 + col] = bf16b(val);
        }
    } else if (col < 2 * NS + NV) {       // w_sv1 * s_j
      const int sj = col - (NS + NV);
      #pragma unroll
      for (int mt = 0; mt < 2; ++mt)
        #pragma unroll
        for (int i = 0; i < 4; ++i) {
          const float wv = (mt ? acc1[i] : acc0[i]) + bias;
          const float val = wv * x_s[(size_t)srcs[mt][i] * NS + sj];
          msg[(size_t)(eblk + mt * 16 + l4 * 4 + i) * 384 + col] = bf16b(val);
        }
    } else {                              // w_vs1 * r0
      #pragma unroll
      for (int mt = 0; mt < 2; ++mt)
        #pragma unroll
        for (int i = 0; i < 4; ++i) {
          const float wv = (mt ? acc1[i] : acc0[i]) + bias;
          const float val = wv * r0a[mt][i];
          msg[(size_t)(eblk + mt * 16 + l4 * 4 + i) * 384 + col] = bf16b(val);
        }
    }
  }
}

// ================= per-node gather + gates + post GEMMs + residual =====
__global__ __launch_bounds__(256) void node_gather_post(
    const __hip_bfloat16* __restrict__ msg, const int* __restrict__ row_start,
    const int* __restrict__ eid, const int* __restrict__ edge_index,
    const float* __restrict__ edge_rshs, const float* __restrict__ x_s,
    const float* __restrict__ x_v, const float* __restrict__ Wqs,
    const float* __restrict__ Wqv, float* __restrict__ out) {
  const int n = blockIdx.x;
  const int t = threadIdx.x;
  const int beg = row_start[n], end = row_start[n + 1];

  int kind[3], moff[3], col_[3], voff[3];
  #pragma unroll
  for (int j = 0; j < 3; ++j) {
    const int c = t + 256 * j;
    if (c < 192) { kind[j] = 0; moff[j] = c; col_[j] = 0; voff[j] = 0; }
    else {
      const int q = c - 192;
      const int row = q / 3, col = q - row * 3;
      col_[j] = col;
      if (row < 128) { kind[j] = 1; moff[j] = 192 + row; voff[j] = 0; }
      else { kind[j] = 2; moff[j] = 320 + (row - 128); voff[j] = (row - 128) * 3 + col; }
    }
  }

  float a0 = 0.f, a1 = 0.f, a2 = 0.f;
  for (int i = beg; i < end; ++i) {
    const int e = eid[i];
    const __hip_bfloat16* m = msg + (size_t)e * 384;
    const int src = edge_index[NEDGE + e];
    const float* xvs = x_v + (size_t)src * (NV * 3);
    float r1[3];
    r1[0] = edge_rshs[e * 4 + 1]; r1[1] = edge_rshs[e * 4 + 2]; r1[2] = edge_rshs[e * 4 + 3];
    {
      float mv = __bfloat162float(m[moff[0]]);
      a0 += (kind[0] == 0) ? mv : (kind[0] == 1 ? mv * r1[col_[0]] : mv * xvs[voff[0]]);
    }
    {
      float mv = __bfloat162float(m[moff[1]]);
      a1 += (kind[1] == 0) ? mv : (kind[1] == 1 ? mv * r1[col_[1]] : mv * xvs[voff[1]]);
    }
    {
      float mv = __bfloat162float(m[moff[2]]);
      a2 += (kind[2] == 0) ? mv : (kind[2] == 1 ? mv * r1[col_[2]] : mv * xvs[voff[2]]);
    }
  }

  __shared__ float accsh[768];
  __shared__ float gs[192];
  __shared__ float gv[576];
  accsh[t] = a0; accsh[t + 256] = a1; accsh[t + 512] = a2;
  __syncthreads();
  if (t < 192) {
    gs[t] = silu_f(accsh[t]);
    const float vx = accsh[192 + 3 * t], vy = accsh[192 + 3 * t + 1], vz = accsh[192 + 3 * t + 2];
    const float nrm = sqrtf(fmaf(vx, vx, fmaf(vy, vy, vz * vz)) + 1e-12f);
    const float sg = 1.f / (1.f + __expf(-nrm));
    gv[3 * t] = vx * sg; gv[3 * t + 1] = vy * sg; gv[3 * t + 2] = vz * sg;
  }
  __syncthreads();

  float* orow = out + (size_t)n * 320;
  for (int o = t; o < 320; o += 256) {
    float a = 0.f;
    if (o < NS) {
      #pragma unroll 8
      for (int u = 0; u < TPC; ++u) a = fmaf(gs[u], Wqs[u * NS + o], a);
      orow[o] = x_s[(size_t)n * NS + o] + a * 0.07216878364870323f;
    } else {
      const int q = o - NS;
      const int vch = q / 3, c = q - vch * 3;
      #pragma unroll 8
      for (int u = 0; u < TPC; ++u) a = fmaf(gv[u * 3 + c], Wqv[u * NV + vch], a);
      orow[o] = x_v[(size_t)n * (NV * 3) + q] + a * 0.07216878364870323f;
    }
  }
}

extern "C" void kernel_launch(void* const* d_in, const int* in_sizes, int n_in,
                              void* d_out, int out_size, void* d_ws, size_t ws_size,
                              hipStream_t stream) {
  const float* node_feat = (const float*)d_in[0];
  const float* edge_attr = (const float*)d_in[1];
  const float* edge_rshs = (const float*)d_in[2];
  const int*   edge_index = (const int*)d_in[3];
  const float* Wps = (const float*)d_in[4];
  const float* bps = (const float*)d_in[5];
  const float* Wpv = (const float*)d_in[6];
  const float* W1  = (const float*)d_in[7];
  const float* b1  = (const float*)d_in[8];
  const float* W2  = (const float*)d_in[9];
  const float* b2  = (const float*)d_in[10];
  const float* Wqs = (const float*)d_in[11];
  const float* Wqv = (const float*)d_in[12];
  float* out = (float*)d_out;

  float* x_s = (float*)d_ws;                                 // 16000*128 f32
  float* x_v = x_s + (size_t)NNODE * NS;                     // 16000*192 f32
  unsigned short* msg = (unsigned short*)(x_v + (size_t)NNODE * NV * 3);  // 256000*384 bf16
  unsigned short* W1P = msg + (size_t)NEDGE * 384;           // 8*64*8 bf16
  unsigned short* W2P = W1P + 8 * 64 * 8;                    // 24*4*64*8 bf16
  int* row_start = (int*)(W2P + 24 * 4 * 64 * 8);            // NNODE+1
  int* cursor = row_start + (NNODE + 1);                     // NNODE
  int* eid = cursor + NNODE;                                 // NEDGE

  hipMemsetAsync(cursor, 0, NNODE * sizeof(int), stream);
  pack_weights<<<192, 256, 0, stream>>>(W1, W2, W1P, W2P);
  node_pre4<<<NNODE / 4, 256, 0, stream>>>(node_feat, Wps, bps, Wpv, x_s, x_v);
  hist_kernel<<<(NEDGE + 255) / 256, 256, 0, stream>>>(edge_index, cursor);
  scan_kernel<<<1, 256, 0, stream>>>(cursor, row_start, cursor);
  scatter_kernel<<<(NEDGE + 255) / 256, 256, 0, stream>>>(edge_index, cursor, eid);
  edge_mlp_mfma<<<NEDGE / EPB, 256, 0, stream>>>(edge_attr, edge_rshs, edge_index,
      W1P, b1, W2P, b2, x_s, x_v, msg);
  node_gather_post<<<NNODE, 256, 0, stream>>>((const __hip_bfloat16*)msg, row_start,
      eid, edge_index, edge_rshs, x_s, x_v, Wqs, Wqv, out);
}

// Round 4
// 547.672 us; speedup vs baseline: 17.5305x; 1.1645x over previous
//
#include <hip/hip_runtime.h>
#include <hip/hip_bf16.h>

#define NS 128
#define NV 64
#define TPC 192
#define NBASIS 16
#define HID 128
#define WOUT 384
#define NNODE 16000
#define NEDGE 256000
#define EPB 32

typedef __attribute__((ext_vector_type(8))) short bf16x8;
typedef __attribute__((ext_vector_type(4))) float f32x4;

__device__ __forceinline__ float silu_f(float x) { return x / (1.0f + __expf(-x)); }
__device__ __forceinline__ unsigned short bf16b(float x) {
  __hip_bfloat16 h = __float2bfloat16(x);
  return *reinterpret_cast<unsigned short*>(&h);
}
__device__ __forceinline__ float bf2f(unsigned short u) {
  return __uint_as_float(((unsigned)u) << 16);
}

// ---------------- pack W1/W2 into MFMA B-fragment order (bf16) ----------------
__global__ __launch_bounds__(256) void pack_weights(
    const float* __restrict__ W1, const float* __restrict__ W2,
    unsigned short* __restrict__ W1P, unsigned short* __restrict__ W2P) {
  const int id = blockIdx.x * 256 + threadIdx.x;
  if (id < 24 * 4 * 64 * 8) {
    const int j = id & 7, lane = (id >> 3) & 63, k = (id >> 9) & 3, nt = id >> 11;
    const int krow = k * 32 + (lane >> 4) * 8 + j;
    const int ncol = nt * 16 + (lane & 15);
    W2P[id] = bf16b(W2[krow * WOUT + ncol]);
  }
  if (id < 8 * 64 * 8) {
    const int j = id & 7, lane = (id >> 3) & 63, nt = id >> 9;
    const int krow = (lane >> 4) * 8 + j;
    const int ncol = nt * 16 + (lane & 15);
    W1P[id] = (krow < NBASIS) ? bf16b(W1[krow * HID + ncol]) : (unsigned short)0;
  }
}

// ---------------- node_pre: 4 nodes/block ----------------
__global__ __launch_bounds__(256) void node_pre4(
    const float* __restrict__ node_feat, const float* __restrict__ Wps,
    const float* __restrict__ bps, const float* __restrict__ Wpv,
    float* __restrict__ x_s, float* __restrict__ x_v) {
  const int n0 = blockIdx.x * 4;
  const int t = threadIdx.x;
  __shared__ float s_sh[4][NS];
  __shared__ float v_sh[4][NV * 3];
  for (int i = t; i < 4 * 320; i += 256) {
    const int nn = i / 320, off = i - nn * 320;
    const float val = node_feat[(size_t)(n0 + nn) * 320 + off];
    if (off < NS) s_sh[nn][off] = val; else v_sh[nn][off - NS] = val;
  }
  __syncthreads();
  for (int o = t; o < 320; o += 256) {
    if (o < NS) {
      float a0 = 0.f, a1 = 0.f, a2 = 0.f, a3 = 0.f;
      #pragma unroll 8
      for (int u = 0; u < NS; ++u) {
        const float wv = Wps[u * NS + o];
        a0 = fmaf(s_sh[0][u], wv, a0); a1 = fmaf(s_sh[1][u], wv, a1);
        a2 = fmaf(s_sh[2][u], wv, a2); a3 = fmaf(s_sh[3][u], wv, a3);
      }
      const float b = bps[o];
      x_s[(size_t)(n0 + 0) * NS + o] = a0 * 0.08838834764831845f + b;
      x_s[(size_t)(n0 + 1) * NS + o] = a1 * 0.08838834764831845f + b;
      x_s[(size_t)(n0 + 2) * NS + o] = a2 * 0.08838834764831845f + b;
      x_s[(size_t)(n0 + 3) * NS + o] = a3 * 0.08838834764831845f + b;
    } else {
      const int q = o - NS;
      const int vch = q / 3, c = q - vch * 3;
      float a0 = 0.f, a1 = 0.f, a2 = 0.f, a3 = 0.f;
      #pragma unroll 8
      for (int u = 0; u < NV; ++u) {
        const float wv = Wpv[u * NV + vch];
        a0 = fmaf(v_sh[0][u * 3 + c], wv, a0); a1 = fmaf(v_sh[1][u * 3 + c], wv, a1);
        a2 = fmaf(v_sh[2][u * 3 + c], wv, a2); a3 = fmaf(v_sh[3][u * 3 + c], wv, a3);
      }
      x_v[(size_t)(n0 + 0) * (NV * 3) + q] = a0 * 0.125f;
      x_v[(size_t)(n0 + 1) * (NV * 3) + q] = a1 * 0.125f;
      x_v[(size_t)(n0 + 2) * (NV * 3) + q] = a2 * 0.125f;
      x_v[(size_t)(n0 + 3) * (NV * 3) + q] = a3 * 0.125f;
    }
  }
}

// ================= CSR build =================
__global__ void hist_kernel(const int* __restrict__ ei, int* __restrict__ cnt) {
  int e = blockIdx.x * 256 + threadIdx.x;
  if (e < NEDGE) atomicAdd(&cnt[ei[e]], 1);
}

__global__ __launch_bounds__(256) void scan_kernel(
    const int* __restrict__ cnt, int* __restrict__ row_start, int* __restrict__ cursor) {
  __shared__ int part[256];
  const int t = threadIdx.x;
  const int base = t * 63;
  int s = 0;
  for (int i = 0; i < 63; ++i) {
    int idx = base + i;
    if (idx < NNODE) s += cnt[idx];
  }
  part[t] = s;
  __syncthreads();
  if (t == 0) {
    int run = 0;
    for (int i = 0; i < 256; ++i) { int x = part[i]; part[i] = run; run += x; }
  }
  __syncthreads();
  int run = part[t];
  for (int i = 0; i < 63; ++i) {
    int idx = base + i;
    if (idx < NNODE) {
      int c = cnt[idx];   // read before overwrite (cnt aliases cursor)
      row_start[idx] = run;
      cursor[idx] = run;
      run += c;
    }
  }
  if (t == 255) row_start[NNODE] = run;
}

// scatter: assign CSR slot, record perm (edge->slot) and per-slot meta {src, r1}
__global__ void scatter_kernel(const int* __restrict__ ei,
                               const float* __restrict__ edge_rshs,
                               int* __restrict__ cursor, int* __restrict__ perm,
                               float4* __restrict__ meta) {
  int e = blockIdx.x * 256 + threadIdx.x;
  if (e < NEDGE) {
    int p = atomicAdd(&cursor[ei[e]], 1);
    perm[e] = p;
    float4 m;
    m.x = __int_as_float(ei[NEDGE + e]);
    m.y = edge_rshs[e * 4 + 1];
    m.z = edge_rshs[e * 4 + 2];
    m.w = edge_rshs[e * 4 + 3];
    meta[p] = m;
  }
}

// ================= edge MLP via MFMA -> bf16 messages at CSR slots ============
// msg layout per slot (384 bf16): [0:192)=msg_s  [192:320)=w_sv1*s_j  [320:384)=w_vs1*r0
__global__ __launch_bounds__(256) void edge_mlp_mfma(
    const float* __restrict__ edge_attr, const float* __restrict__ edge_rshs,
    const int* __restrict__ edge_index, const int* __restrict__ perm,
    const unsigned short* __restrict__ W1P, const float* __restrict__ b1,
    const unsigned short* __restrict__ W2P, const float* __restrict__ b2,
    const float* __restrict__ x_s, const float* __restrict__ x_v,
    unsigned short* __restrict__ msg) {
  __shared__ __align__(16) unsigned short ea_lds[32 * 48];
  __shared__ __align__(16) unsigned short Hs[32 * 136];
  __shared__ int src_sh[32];
  __shared__ int slot_sh[32];
  __shared__ float rsh_sh[32][4];
  const int t = threadIdx.x;
  const int lane = t & 63;
  const int w = t >> 6;
  const int l15 = lane & 15;
  const int l4 = lane >> 4;
  const int eblk = blockIdx.x * EPB;

  for (int i = t; i < 32 * 48; i += 256) {
    const int e = i / 48, k = i - e * 48;
    ea_lds[i] = (k < NBASIS) ? bf16b(edge_attr[(size_t)(eblk + e) * NBASIS + k])
                             : (unsigned short)0;
  }
  if (t < 32 * 4) rsh_sh[t >> 2][t & 3] = edge_rshs[(size_t)eblk * 4 + t];
  if (t < 32) {
    src_sh[t] = edge_index[NEDGE + eblk + t];
    slot_sh[t] = perm[eblk + t];
  }
  __syncthreads();

  // GEMM1: H = silu(ea @ W1 + b1)
  {
    const int mt = w & 1, ch = w >> 1;
    const bf16x8 afrag = *(const bf16x8*)&ea_lds[(mt * 16 + l15) * 48 + l4 * 8];
    #pragma unroll
    for (int nt = 0; nt < 4; ++nt) {
      const int ntg = ch * 4 + nt;
      const bf16x8 bfrag = *(const bf16x8*)&W1P[((size_t)ntg * 64 + lane) * 8];
      f32x4 d = {0.f, 0.f, 0.f, 0.f};
      d = __builtin_amdgcn_mfma_f32_16x16x32_bf16(afrag, bfrag, d, 0, 0, 0);
      const int col = ntg * 16 + l15;
      const float bias = b1[col];
      #pragma unroll
      for (int i = 0; i < 4; ++i) {
        const int e = mt * 16 + l4 * 4 + i;
        Hs[e * 136 + col] = bf16b(silu_f(d[i] + bias));
      }
    }
  }
  __syncthreads();

  // preload A-frags + per-lane edge metadata
  bf16x8 afr[2][4];
  #pragma unroll
  for (int mt = 0; mt < 2; ++mt)
    #pragma unroll
    for (int k = 0; k < 4; ++k)
      afr[mt][k] = *(const bf16x8*)&Hs[(mt * 16 + l15) * 136 + k * 32 + l4 * 8];

  int srcs[2][4], slots[2][4];
  float r0a[2][4], r1xa[2][4], r1ya[2][4], r1za[2][4];
  #pragma unroll
  for (int mt = 0; mt < 2; ++mt)
    #pragma unroll
    for (int i = 0; i < 4; ++i) {
      const int e = mt * 16 + l4 * 4 + i;
      srcs[mt][i] = src_sh[e];
      slots[mt][i] = slot_sh[e];
      r0a[mt][i] = rsh_sh[e][0];
      r1xa[mt][i] = rsh_sh[e][1];
      r1ya[mt][i] = rsh_sh[e][2];
      r1za[mt][i] = rsh_sh[e][3];
    }

  // GEMM2 + epilogue: wave w owns ntiles [w*6, w*6+6)
  for (int nn = 0; nn < 6; ++nn) {
    const int nt = w * 6 + nn;
    bf16x8 bfr[4];
    #pragma unroll
    for (int k = 0; k < 4; ++k)
      bfr[k] = *(const bf16x8*)&W2P[(((size_t)nt * 4 + k) * 64 + lane) * 8];
    f32x4 acc0 = {0.f, 0.f, 0.f, 0.f}, acc1 = {0.f, 0.f, 0.f, 0.f};
    #pragma unroll
    for (int k = 0; k < 4; ++k) {
      acc0 = __builtin_amdgcn_mfma_f32_16x16x32_bf16(afr[0][k], bfr[k], acc0, 0, 0, 0);
      acc1 = __builtin_amdgcn_mfma_f32_16x16x32_bf16(afr[1][k], bfr[k], acc1, 0, 0, 0);
    }
    const int col = nt * 16 + l15;
    const float bias = b2[col];
    if (col < NS) {                       // w_ss0 * s_j * r0
      #pragma unroll
      for (int mt = 0; mt < 2; ++mt)
        #pragma unroll
        for (int i = 0; i < 4; ++i) {
          const float wv = (mt ? acc1[i] : acc0[i]) + bias;
          const float val = wv * x_s[(size_t)srcs[mt][i] * NS + col] * r0a[mt][i];
          msg[(size_t)slots[mt][i] * 384 + col] = bf16b(val);
        }
    } else if (col < NS + NV) {           // w_vv0 * <v_j, r1> / sqrt3
      const int u = col - NS;
      #pragma unroll
      for (int mt = 0; mt < 2; ++mt)
        #pragma unroll
        for (int i = 0; i < 4; ++i) {
          const float wv = (mt ? acc1[i] : acc0[i]) + bias;
          const float* vj = x_v + (size_t)srcs[mt][i] * (NV * 3) + u * 3;
          const float vd = vj[0] * r1xa[mt][i] + vj[1] * r1ya[mt][i] + vj[2] * r1za[mt][i];
          const float val = wv * vd * 0.5773502691896258f;
          msg[(size_t)slots[mt][i] * 384 + col] = bf16b(val);
        }
    } else if (col < 2 * NS + NV) {       // w_sv1 * s_j
      const int sj = col - (NS + NV);
      #pragma unroll
      for (int mt = 0; mt < 2; ++mt)
        #pragma unroll
        for (int i = 0; i < 4; ++i) {
          const float wv = (mt ? acc1[i] : acc0[i]) + bias;
          const float val = wv * x_s[(size_t)srcs[mt][i] * NS + sj];
          msg[(size_t)slots[mt][i] * 384 + col] = bf16b(val);
        }
    } else {                              // w_vs1 * r0
      #pragma unroll
      for (int mt = 0; mt < 2; ++mt)
        #pragma unroll
        for (int i = 0; i < 4; ++i) {
          const float wv = (mt ? acc1[i] : acc0[i]) + bias;
          const float val = wv * r0a[mt][i];
          msg[(size_t)slots[mt][i] * 384 + col] = bf16b(val);
        }
    }
  }
}

// ================= per-node streaming gather + gates + post GEMMs + residual ===
__global__ __launch_bounds__(256) void node_gather_post(
    const unsigned short* __restrict__ msg, const int* __restrict__ row_start,
    const float4* __restrict__ meta, const float* __restrict__ x_s,
    const float* __restrict__ x_v, const float* __restrict__ Wqs,
    const float* __restrict__ Wqv, float* __restrict__ out) {
  const int n = blockIdx.x;
  const int t = threadIdx.x;
  const int beg = row_start[n], end = row_start[n + 1];

  int kind[3], moff[3], col_[3], voff[3];
  #pragma unroll
  for (int j = 0; j < 3; ++j) {
    const int c = t + 256 * j;
    if (c < 192) { kind[j] = 0; moff[j] = c; col_[j] = 0; voff[j] = 0; }
    else {
      const int q = c - 192;
      const int row = q / 3, col = q - row * 3;
      col_[j] = col;
      if (row < 128) { kind[j] = 1; moff[j] = 192 + row; voff[j] = 0; }
      else { kind[j] = 2; moff[j] = 320 + (row - 128); voff[j] = (row - 128) * 3 + col; }
    }
  }

  float a[3] = {0.f, 0.f, 0.f};
  // 2-deep software pipeline: meta+msg prefetched 2 ahead, x_v 1 ahead
  float4 mC = {0, 0, 0, 0}, mN = {0, 0, 0, 0};
  unsigned short vC[3] = {0, 0, 0}, vN[3] = {0, 0, 0};
  float xvC[3] = {0.f, 0.f, 0.f};

  const int len = end - beg;
  if (len > 0) {
    mC = meta[beg];
    #pragma unroll
    for (int j = 0; j < 3; ++j) vC[j] = msg[(size_t)beg * 384 + moff[j]];
    const int srcC = __float_as_int(mC.x);
    #pragma unroll
    for (int j = 0; j < 3; ++j)
      if (kind[j] == 2) xvC[j] = x_v[(size_t)srcC * (NV * 3) + voff[j]];
  }
  if (len > 1) {
    mN = meta[beg + 1];
    #pragma unroll
    for (int j = 0; j < 3; ++j) vN[j] = msg[(size_t)(beg + 1) * 384 + moff[j]];
  }

  for (int i = beg; i < end; ++i) {
    float xvN[3] = {0.f, 0.f, 0.f};
    if (i + 1 < end) {
      const int srcN = __float_as_int(mN.x);
      #pragma unroll
      for (int j = 0; j < 3; ++j)
        if (kind[j] == 2) xvN[j] = x_v[(size_t)srcN * (NV * 3) + voff[j]];
    }
    float4 m2 = {0, 0, 0, 0};
    unsigned short v2[3] = {0, 0, 0};
    if (i + 2 < end) {
      m2 = meta[i + 2];
      #pragma unroll
      for (int j = 0; j < 3; ++j) v2[j] = msg[(size_t)(i + 2) * 384 + moff[j]];
    }
    const float r1v0 = mC.y, r1v1 = mC.z, r1v2 = mC.w;
    #pragma unroll
    for (int j = 0; j < 3; ++j) {
      const float mv = bf2f(vC[j]);
      const float r1sel = (col_[j] == 0) ? r1v0 : (col_[j] == 1 ? r1v1 : r1v2);
      const float f = (kind[j] == 0) ? 1.0f : (kind[j] == 1 ? r1sel : xvC[j]);
      a[j] = fmaf(mv, f, a[j]);
    }
    mC = mN; mN = m2;
    #pragma unroll
    for (int j = 0; j < 3; ++j) { vC[j] = vN[j]; vN[j] = v2[j]; xvC[j] = xvN[j]; }
  }

  __shared__ float accsh[768];
  __shared__ float gs[192];
  __shared__ float gv[576];
  accsh[t] = a[0]; accsh[t + 256] = a[1]; accsh[t + 512] = a[2];
  __syncthreads();
  if (t < 192) {
    gs[t] = silu_f(accsh[t]);
    const float vx = accsh[192 + 3 * t], vy = accsh[192 + 3 * t + 1], vz = accsh[192 + 3 * t + 2];
    const float nrm = sqrtf(fmaf(vx, vx, fmaf(vy, vy, vz * vz)) + 1e-12f);
    const float sg = 1.f / (1.f + __expf(-nrm));
    gv[3 * t] = vx * sg; gv[3 * t + 1] = vy * sg; gv[3 * t + 2] = vz * sg;
  }
  __syncthreads();

  float* orow = out + (size_t)n * 320;
  for (int o = t; o < 320; o += 256) {
    float a2 = 0.f;
    if (o < NS) {
      #pragma unroll 8
      for (int u = 0; u < TPC; ++u) a2 = fmaf(gs[u], Wqs[u * NS + o], a2);
      orow[o] = x_s[(size_t)n * NS + o] + a2 * 0.07216878364870323f;
    } else {
      const int q = o - NS;
      const int vch = q / 3, c = q - vch * 3;
      #pragma unroll 8
      for (int u = 0; u < TPC; ++u) a2 = fmaf(gv[u * 3 + c], Wqv[u * NV + vch], a2);
      orow[o] = x_v[(size_t)n * (NV * 3) + q] + a2 * 0.07216878364870323f;
    }
  }
}

extern "C" void kernel_launch(void* const* d_in, const int* in_sizes, int n_in,
                              void* d_out, int out_size, void* d_ws, size_t ws_size,
                              hipStream_t stream) {
  const float* node_feat = (const float*)d_in[0];
  const float* edge_attr = (const float*)d_in[1];
  const float* edge_rshs = (const float*)d_in[2];
  const int*   edge_index = (const int*)d_in[3];
  const float* Wps = (const float*)d_in[4];
  const float* bps = (const float*)d_in[5];
  const float* Wpv = (const float*)d_in[6];
  const float* W1  = (const float*)d_in[7];
  const float* b1  = (const float*)d_in[8];
  const float* W2  = (const float*)d_in[9];
  const float* b2  = (const float*)d_in[10];
  const float* Wqs = (const float*)d_in[11];
  const float* Wqv = (const float*)d_in[12];
  float* out = (float*)d_out;

  float* x_s = (float*)d_ws;                                            // 16000*128 f32
  float* x_v = x_s + (size_t)NNODE * NS;                                // 16000*192 f32
  unsigned short* msg = (unsigned short*)(x_v + (size_t)NNODE * NV * 3);// 256000*384 bf16
  unsigned short* W1P = msg + (size_t)NEDGE * 384;                      // 4096 bf16
  unsigned short* W2P = W1P + 8 * 64 * 8;                               // 49152 bf16
  float4* meta = (float4*)(W2P + 24 * 4 * 64 * 8);                      // NEDGE float4 (16B-aligned)
  int* row_start = (int*)(meta + NEDGE);                                // NNODE+1
  int* cursor = row_start + (NNODE + 1);                                // NNODE
  int* perm = cursor + NNODE;                                           // NEDGE

  hipMemsetAsync(cursor, 0, NNODE * sizeof(int), stream);
  pack_weights<<<192, 256, 0, stream>>>(W1, W2, W1P, W2P);
  node_pre4<<<NNODE / 4, 256, 0, stream>>>(node_feat, Wps, bps, Wpv, x_s, x_v);
  hist_kernel<<<(NEDGE + 255) / 256, 256, 0, stream>>>(edge_index, cursor);
  scan_kernel<<<1, 256, 0, stream>>>(cursor, row_start, cursor);
  scatter_kernel<<<(NEDGE + 255) / 256, 256, 0, stream>>>(edge_index, edge_rshs,
      cursor, perm, meta);
  edge_mlp_mfma<<<NEDGE / EPB, 256, 0, stream>>>(edge_attr, edge_rshs, edge_index,
      perm, W1P, b1, W2P, b2, x_s, x_v, msg);
  node_gather_post<<<NNODE, 256, 0, stream>>>(msg, row_start, meta, x_s, x_v,
      Wqs, Wqv, out);
}

// Round 5
// 448.683 us; speedup vs baseline: 21.3980x; 1.2206x over previous
//
#include <hip/hip_runtime.h>
#include <hip/hip_bf16.h>

#define NS 128
#define NV 64
#define TPC 192
#define NBASIS 16
#define HID 128
#define WOUT 384
#define NNODE 16000
#define NEDGE 256000
#define EPB 32

typedef __attribute__((ext_vector_type(8))) short bf16x8;
typedef __attribute__((ext_vector_type(8))) unsigned short u16x8;
typedef __attribute__((ext_vector_type(4))) float f32x4;

__device__ __forceinline__ float silu_f(float x) { return x / (1.0f + __expf(-x)); }
__device__ __forceinline__ unsigned short bf16b(float x) {
  __hip_bfloat16 h = __float2bfloat16(x);
  return *reinterpret_cast<unsigned short*>(&h);
}
__device__ __forceinline__ float bf2f(unsigned short u) {
  return __uint_as_float(((unsigned)u) << 16);
}

// ---------------- pack W1/W2 into MFMA B-fragment order (bf16) ----------------
__global__ __launch_bounds__(256) void pack_weights(
    const float* __restrict__ W1, const float* __restrict__ W2,
    unsigned short* __restrict__ W1P, unsigned short* __restrict__ W2P) {
  const int id = blockIdx.x * 256 + threadIdx.x;
  if (id < 24 * 4 * 64 * 8) {
    const int j = id & 7, lane = (id >> 3) & 63, k = (id >> 9) & 3, nt = id >> 11;
    const int krow = k * 32 + (lane >> 4) * 8 + j;
    const int ncol = nt * 16 + (lane & 15);
    W2P[id] = bf16b(W2[krow * WOUT + ncol]);
  }
  if (id < 8 * 64 * 8) {
    const int j = id & 7, lane = (id >> 3) & 63, nt = id >> 9;
    const int krow = (lane >> 4) * 8 + j;
    const int ncol = nt * 16 + (lane & 15);
    W1P[id] = (krow < NBASIS) ? bf16b(W1[krow * HID + ncol]) : (unsigned short)0;
  }
}

// ---------------- node_pre: 4 nodes/block ----------------
__global__ __launch_bounds__(256) void node_pre4(
    const float* __restrict__ node_feat, const float* __restrict__ Wps,
    const float* __restrict__ bps, const float* __restrict__ Wpv,
    float* __restrict__ x_s, float* __restrict__ x_v) {
  const int n0 = blockIdx.x * 4;
  const int t = threadIdx.x;
  __shared__ float s_sh[4][NS];
  __shared__ float v_sh[4][NV * 3];
  for (int i = t; i < 4 * 320; i += 256) {
    const int nn = i / 320, off = i - nn * 320;
    const float val = node_feat[(size_t)(n0 + nn) * 320 + off];
    if (off < NS) s_sh[nn][off] = val; else v_sh[nn][off - NS] = val;
  }
  __syncthreads();
  for (int o = t; o < 320; o += 256) {
    if (o < NS) {
      float a0 = 0.f, a1 = 0.f, a2 = 0.f, a3 = 0.f;
      #pragma unroll 8
      for (int u = 0; u < NS; ++u) {
        const float wv = Wps[u * NS + o];
        a0 = fmaf(s_sh[0][u], wv, a0); a1 = fmaf(s_sh[1][u], wv, a1);
        a2 = fmaf(s_sh[2][u], wv, a2); a3 = fmaf(s_sh[3][u], wv, a3);
      }
      const float b = bps[o];
      x_s[(size_t)(n0 + 0) * NS + o] = a0 * 0.08838834764831845f + b;
      x_s[(size_t)(n0 + 1) * NS + o] = a1 * 0.08838834764831845f + b;
      x_s[(size_t)(n0 + 2) * NS + o] = a2 * 0.08838834764831845f + b;
      x_s[(size_t)(n0 + 3) * NS + o] = a3 * 0.08838834764831845f + b;
    } else {
      const int q = o - NS;
      const int vch = q / 3, c = q - vch * 3;
      float a0 = 0.f, a1 = 0.f, a2 = 0.f, a3 = 0.f;
      #pragma unroll 8
      for (int u = 0; u < NV; ++u) {
        const float wv = Wpv[u * NV + vch];
        a0 = fmaf(v_sh[0][u * 3 + c], wv, a0); a1 = fmaf(v_sh[1][u * 3 + c], wv, a1);
        a2 = fmaf(v_sh[2][u * 3 + c], wv, a2); a3 = fmaf(v_sh[3][u * 3 + c], wv, a3);
      }
      x_v[(size_t)(n0 + 0) * (NV * 3) + q] = a0 * 0.125f;
      x_v[(size_t)(n0 + 1) * (NV * 3) + q] = a1 * 0.125f;
      x_v[(size_t)(n0 + 2) * (NV * 3) + q] = a2 * 0.125f;
      x_v[(size_t)(n0 + 3) * (NV * 3) + q] = a3 * 0.125f;
    }
  }
}

// ================= CSR build =================
__global__ void hist_kernel(const int* __restrict__ ei, int* __restrict__ cnt) {
  int e = blockIdx.x * 256 + threadIdx.x;
  if (e < NEDGE) atomicAdd(&cnt[ei[e]], 1);
}

__global__ __launch_bounds__(256) void scan_kernel(
    const int* __restrict__ cnt, int* __restrict__ row_start, int* __restrict__ cursor) {
  __shared__ int part[256];
  const int t = threadIdx.x;
  const int base = t * 63;
  int s = 0;
  for (int i = 0; i < 63; ++i) {
    int idx = base + i;
    if (idx < NNODE) s += cnt[idx];
  }
  part[t] = s;
  __syncthreads();
  if (t == 0) {
    int run = 0;
    for (int i = 0; i < 256; ++i) { int x = part[i]; part[i] = run; run += x; }
  }
  __syncthreads();
  int run = part[t];
  for (int i = 0; i < 63; ++i) {
    int idx = base + i;
    if (idx < NNODE) {
      int c = cnt[idx];   // read before overwrite (cnt aliases cursor)
      row_start[idx] = run;
      cursor[idx] = run;
      run += c;
    }
  }
  if (t == 255) row_start[NNODE] = run;
}

// scatter: assign CSR slot, record perm (edge->slot) and per-slot meta {src, r1}
__global__ void scatter_kernel(const int* __restrict__ ei,
                               const float* __restrict__ edge_rshs,
                               int* __restrict__ cursor, int* __restrict__ perm,
                               float4* __restrict__ meta) {
  int e = blockIdx.x * 256 + threadIdx.x;
  if (e < NEDGE) {
    int p = atomicAdd(&cursor[ei[e]], 1);
    perm[e] = p;
    float4 m;
    m.x = __int_as_float(ei[NEDGE + e]);
    m.y = edge_rshs[e * 4 + 1];
    m.z = edge_rshs[e * 4 + 2];
    m.w = edge_rshs[e * 4 + 3];
    meta[p] = m;
  }
}

// ================= edge MLP via MFMA -> bf16 messages at CSR slots ============
// msg layout per slot (384 bf16): [0:192)=msg_s  [192:320)=w_sv1*s_j  [320:384)=w_vs1*r0
__global__ __launch_bounds__(256) void edge_mlp_mfma(
    const float* __restrict__ edge_attr, const float* __restrict__ edge_rshs,
    const int* __restrict__ edge_index, const int* __restrict__ perm,
    const unsigned short* __restrict__ W1P, const float* __restrict__ b1,
    const unsigned short* __restrict__ W2P, const float* __restrict__ b2,
    const float* __restrict__ x_s, const float* __restrict__ x_v,
    unsigned short* __restrict__ msg) {
  // phase-separated union: {ea, Hs} live until A-frag preload; msg staging after
  union SMU {
    struct { unsigned short ea[32 * 48]; unsigned short Hs[32 * 136]; } p1;
    unsigned short msgb[32 * 392];
  };
  __shared__ __align__(16) SMU sm;
  __shared__ unsigned short sj[32][136];   // bf16 s_j rows
  __shared__ unsigned short vd[32][72];    // bf16 <v_j,r1>*inv_sqrt3
  __shared__ int src_sh[32];
  __shared__ int slot_sh[32];
  __shared__ float rsh_sh[32][4];
  const int t = threadIdx.x;
  const int lane = t & 63;
  const int w = t >> 6;
  const int l15 = lane & 15;
  const int l4 = lane >> 4;
  const int eblk = blockIdx.x * EPB;

  // ---- phase 0: stage edge_attr + metadata
  for (int i = t; i < 32 * 48; i += 256) {
    const int e = i / 48, k = i - e * 48;
    sm.p1.ea[i] = (k < NBASIS) ? bf16b(edge_attr[(size_t)(eblk + e) * NBASIS + k])
                               : (unsigned short)0;
  }
  if (t < 32 * 4) rsh_sh[t >> 2][t & 3] = edge_rshs[(size_t)eblk * 4 + t];
  if (t < 32) {
    src_sh[t] = edge_index[NEDGE + eblk + t];
    slot_sh[t] = perm[eblk + t];
  }
  __syncthreads();

  // ---- phase 1: GEMM1 (H = silu(ea@W1+b1)) + cooperative sj/vd staging
  {
    const int mt = w & 1, ch = w >> 1;
    const bf16x8 afrag = *(const bf16x8*)&sm.p1.ea[(mt * 16 + l15) * 48 + l4 * 8];
    #pragma unroll
    for (int nt = 0; nt < 4; ++nt) {
      const int ntg = ch * 4 + nt;
      const bf16x8 bfrag = *(const bf16x8*)&W1P[((size_t)ntg * 64 + lane) * 8];
      f32x4 d = {0.f, 0.f, 0.f, 0.f};
      d = __builtin_amdgcn_mfma_f32_16x16x32_bf16(afrag, bfrag, d, 0, 0, 0);
      const int col = ntg * 16 + l15;
      const float bias = b1[col];
      #pragma unroll
      for (int i = 0; i < 4; ++i) {
        const int e = mt * 16 + l4 * 4 + i;
        sm.p1.Hs[e * 136 + col] = bf16b(silu_f(d[i] + bias));
      }
    }
  }
  // stage s_j rows (coalesced f32 reads -> bf16 LDS)
  #pragma unroll
  for (int p = 0; p < 16; ++p) {
    const int idx = p * 256 + t;
    const int e = idx >> 7, c = idx & 127;
    sj[e][c] = bf16b(x_s[(size_t)src_sh[e] * NS + c]);
  }
  // stage vd[e][u] = <v_j[u], r1> * inv_sqrt3
  #pragma unroll
  for (int p = 0; p < 8; ++p) {
    const int idx = p * 256 + t;
    const int e = idx >> 6, u = idx & 63;
    const float* vp = x_v + (size_t)src_sh[e] * (NV * 3) + u * 3;
    const float dotv = vp[0] * rsh_sh[e][1] + vp[1] * rsh_sh[e][2] + vp[2] * rsh_sh[e][3];
    vd[e][u] = bf16b(dotv * 0.5773502691896258f);
  }
  __syncthreads();

  // ---- phase 2: preload A-frags from Hs (then Hs is dead)
  bf16x8 afr[2][4];
  #pragma unroll
  for (int mt = 0; mt < 2; ++mt)
    #pragma unroll
    for (int k = 0; k < 4; ++k)
      afr[mt][k] = *(const bf16x8*)&sm.p1.Hs[(mt * 16 + l15) * 136 + k * 32 + l4 * 8];

  float r0a[2][4];
  #pragma unroll
  for (int mt = 0; mt < 2; ++mt)
    #pragma unroll
    for (int i = 0; i < 4; ++i) r0a[mt][i] = rsh_sh[mt * 16 + l4 * 4 + i][0];
  __syncthreads();   // everyone done reading Hs; msgb region now writable

  // ---- phase 3: GEMM2 + in-LDS epilogue. wave w owns ntiles [w*6, w*6+6)
  for (int nn = 0; nn < 6; ++nn) {
    const int nt = w * 6 + nn;
    bf16x8 bfr[4];
    #pragma unroll
    for (int k = 0; k < 4; ++k)
      bfr[k] = *(const bf16x8*)&W2P[(((size_t)nt * 4 + k) * 64 + lane) * 8];
    f32x4 acc0 = {0.f, 0.f, 0.f, 0.f}, acc1 = {0.f, 0.f, 0.f, 0.f};
    #pragma unroll
    for (int k = 0; k < 4; ++k) {
      acc0 = __builtin_amdgcn_mfma_f32_16x16x32_bf16(afr[0][k], bfr[k], acc0, 0, 0, 0);
      acc1 = __builtin_amdgcn_mfma_f32_16x16x32_bf16(afr[1][k], bfr[k], acc1, 0, 0, 0);
    }
    const int col = nt * 16 + l15;
    const float bias = b2[col];
    if (col < NS) {                       // w_ss0 * s_j * r0
      #pragma unroll
      for (int mt = 0; mt < 2; ++mt)
        #pragma unroll
        for (int i = 0; i < 4; ++i) {
          const int e = mt * 16 + l4 * 4 + i;
          const float wv = (mt ? acc1[i] : acc0[i]) + bias;
          sm.msgb[e * 392 + col] = bf16b(wv * bf2f(sj[e][col]) * r0a[mt][i]);
        }
    } else if (col < NS + NV) {           // w_vv0 * <v_j,r1>/sqrt3
      const int u = col - NS;
      #pragma unroll
      for (int mt = 0; mt < 2; ++mt)
        #pragma unroll
        for (int i = 0; i < 4; ++i) {
          const int e = mt * 16 + l4 * 4 + i;
          const float wv = (mt ? acc1[i] : acc0[i]) + bias;
          sm.msgb[e * 392 + col] = bf16b(wv * bf2f(vd[e][u]));
        }
    } else if (col < 2 * NS + NV) {       // w_sv1 * s_j
      const int sjc = col - (NS + NV);
      #pragma unroll
      for (int mt = 0; mt < 2; ++mt)
        #pragma unroll
        for (int i = 0; i < 4; ++i) {
          const int e = mt * 16 + l4 * 4 + i;
          const float wv = (mt ? acc1[i] : acc0[i]) + bias;
          sm.msgb[e * 392 + col] = bf16b(wv * bf2f(sj[e][sjc]));
        }
    } else {                              // w_vs1 * r0
      #pragma unroll
      for (int mt = 0; mt < 2; ++mt)
        #pragma unroll
        for (int i = 0; i < 4; ++i) {
          const int e = mt * 16 + l4 * 4 + i;
          const float wv = (mt ? acc1[i] : acc0[i]) + bias;
          sm.msgb[e * 392 + col] = bf16b(wv * r0a[mt][i]);
        }
    }
  }
  __syncthreads();

  // ---- phase 4: coalesced write-out, 768 B per edge row at its CSR slot
  #pragma unroll
  for (int p = 0; p < 6; ++p) {
    const int idx = p * 256 + t;
    const int e = idx / 48, c = idx - e * 48;
    const u16x8 vv = *(const u16x8*)&sm.msgb[e * 392 + c * 8];
    *(u16x8*)&msg[(size_t)slot_sh[e] * 384 + c * 8] = vv;
  }
}

// ================= per-node streaming gather + gates + post GEMMs + residual ===
__global__ __launch_bounds__(256) void node_gather_post(
    const unsigned short* __restrict__ msg, const int* __restrict__ row_start,
    const float4* __restrict__ meta, const float* __restrict__ x_s,
    const float* __restrict__ x_v, const float* __restrict__ Wqs,
    const float* __restrict__ Wqv, float* __restrict__ out) {
  const int n = blockIdx.x;
  const int t = threadIdx.x;
  const int beg = row_start[n], end = row_start[n + 1];

  int kind[3], moff[3], col_[3], voff[3];
  #pragma unroll
  for (int j = 0; j < 3; ++j) {
    const int c = t + 256 * j;
    if (c < 192) { kind[j] = 0; moff[j] = c; col_[j] = 0; voff[j] = 0; }
    else {
      const int q = c - 192;
      const int row = q / 3, col = q - row * 3;
      col_[j] = col;
      if (row < 128) { kind[j] = 1; moff[j] = 192 + row; voff[j] = 0; }
      else { kind[j] = 2; moff[j] = 320 + (row - 128); voff[j] = (row - 128) * 3 + col; }
    }
  }

  float a[3] = {0.f, 0.f, 0.f};
  float4 mC = {0, 0, 0, 0}, mN = {0, 0, 0, 0};
  unsigned short vC[3] = {0, 0, 0}, vN[3] = {0, 0, 0};
  float xvC[3] = {0.f, 0.f, 0.f};

  const int len = end - beg;
  if (len > 0) {
    mC = meta[beg];
    #pragma unroll
    for (int j = 0; j < 3; ++j) vC[j] = msg[(size_t)beg * 384 + moff[j]];
    const int srcC = __float_as_int(mC.x);
    #pragma unroll
    for (int j = 0; j < 3; ++j)
      if (kind[j] == 2) xvC[j] = x_v[(size_t)srcC * (NV * 3) + voff[j]];
  }
  if (len > 1) {
    mN = meta[beg + 1];
    #pragma unroll
    for (int j = 0; j < 3; ++j) vN[j] = msg[(size_t)(beg + 1) * 384 + moff[j]];
  }

  for (int i = beg; i < end; ++i) {
    float xvN[3] = {0.f, 0.f, 0.f};
    if (i + 1 < end) {
      const int srcN = __float_as_int(mN.x);
      #pragma unroll
      for (int j = 0; j < 3; ++j)
        if (kind[j] == 2) xvN[j] = x_v[(size_t)srcN * (NV * 3) + voff[j]];
    }
    float4 m2 = {0, 0, 0, 0};
    unsigned short v2[3] = {0, 0, 0};
    if (i + 2 < end) {
      m2 = meta[i + 2];
      #pragma unroll
      for (int j = 0; j < 3; ++j) v2[j] = msg[(size_t)(i + 2) * 384 + moff[j]];
    }
    const float r1v0 = mC.y, r1v1 = mC.z, r1v2 = mC.w;
    #pragma unroll
    for (int j = 0; j < 3; ++j) {
      const float mv = bf2f(vC[j]);
      const float r1sel = (col_[j] == 0) ? r1v0 : (col_[j] == 1 ? r1v1 : r1v2);
      const float f = (kind[j] == 0) ? 1.0f : (kind[j] == 1 ? r1sel : xvC[j]);
      a[j] = fmaf(mv, f, a[j]);
    }
    mC = mN; mN = m2;
    #pragma unroll
    for (int j = 0; j < 3; ++j) { vC[j] = vN[j]; vN[j] = v2[j]; xvC[j] = xvN[j]; }
  }

  __shared__ float accsh[768];
  __shared__ float gs[192];
  __shared__ float gv[576];
  accsh[t] = a[0]; accsh[t + 256] = a[1]; accsh[t + 512] = a[2];
  __syncthreads();
  if (t < 192) {
    gs[t] = silu_f(accsh[t]);
    const float vx = accsh[192 + 3 * t], vy = accsh[192 + 3 * t + 1], vz = accsh[192 + 3 * t + 2];
    const float nrm = sqrtf(fmaf(vx, vx, fmaf(vy, vy, vz * vz)) + 1e-12f);
    const float sg = 1.f / (1.f + __expf(-nrm));
    gv[3 * t] = vx * sg; gv[3 * t + 1] = vy * sg; gv[3 * t + 2] = vz * sg;
  }
  __syncthreads();

  float* orow = out + (size_t)n * 320;
  for (int o = t; o < 320; o += 256) {
    float a2 = 0.f;
    if (o < NS) {
      #pragma unroll 8
      for (int u = 0; u < TPC; ++u) a2 = fmaf(gs[u], Wqs[u * NS + o], a2);
      orow[o] = x_s[(size_t)n * NS + o] + a2 * 0.07216878364870323f;
    } else {
      const int q = o - NS;
      const int vch = q / 3, c = q - vch * 3;
      #pragma unroll 8
      for (int u = 0; u < TPC; ++u) a2 = fmaf(gv[u * 3 + c], Wqv[u * NV + vch], a2);
      orow[o] = x_v[(size_t)n * (NV * 3) + q] + a2 * 0.07216878364870323f;
    }
  }
}

extern "C" void kernel_launch(void* const* d_in, const int* in_sizes, int n_in,
                              void* d_out, int out_size, void* d_ws, size_t ws_size,
                              hipStream_t stream) {
  const float* node_feat = (const float*)d_in[0];
  const float* edge_attr = (const float*)d_in[1];
  const float* edge_rshs = (const float*)d_in[2];
  const int*   edge_index = (const int*)d_in[3];
  const float* Wps = (const float*)d_in[4];
  const float* bps = (const float*)d_in[5];
  const float* Wpv = (const float*)d_in[6];
  const float* W1  = (const float*)d_in[7];
  const float* b1  = (const float*)d_in[8];
  const float* W2  = (const float*)d_in[9];
  const float* b2  = (const float*)d_in[10];
  const float* Wqs = (const float*)d_in[11];
  const float* Wqv = (const float*)d_in[12];
  float* out = (float*)d_out;

  float* x_s = (float*)d_ws;                                            // 16000*128 f32
  float* x_v = x_s + (size_t)NNODE * NS;                                // 16000*192 f32
  unsigned short* msg = (unsigned short*)(x_v + (size_t)NNODE * NV * 3);// 256000*384 bf16
  unsigned short* W1P = msg + (size_t)NEDGE * 384;                      // 4096 bf16
  unsigned short* W2P = W1P + 8 * 64 * 8;                               // 49152 bf16
  float4* meta = (float4*)(W2P + 24 * 4 * 64 * 8);                      // NEDGE float4
  int* row_start = (int*)(meta + NEDGE);                                // NNODE+1
  int* cursor = row_start + (NNODE + 1);                                // NNODE
  int* perm = cursor + NNODE;                                           // NEDGE

  hipMemsetAsync(cursor, 0, NNODE * sizeof(int), stream);
  pack_weights<<<192, 256, 0, stream>>>(W1, W2, W1P, W2P);
  node_pre4<<<NNODE / 4, 256, 0, stream>>>(node_feat, Wps, bps, Wpv, x_s, x_v);
  hist_kernel<<<(NEDGE + 255) / 256, 256, 0, stream>>>(edge_index, cursor);
  scan_kernel<<<1, 256, 0, stream>>>(cursor, row_start, cursor);
  scatter_kernel<<<(NEDGE + 255) / 256, 256, 0, stream>>>(edge_index, edge_rshs,
      cursor, perm, meta);
  edge_mlp_mfma<<<NEDGE / EPB, 256, 0, stream>>>(edge_attr, edge_rshs, edge_index,
      perm, W1P, b1, W2P, b2, x_s, x_v, msg);
  node_gather_post<<<NNODE, 256, 0, stream>>>(msg, row_start, meta, x_s, x_v,
      Wqs, Wqv, out);
}

// Round 6
// 403.850 us; speedup vs baseline: 23.7735x; 1.1110x over previous
//
#include <hip/hip_runtime.h>
#include <hip/hip_bf16.h>

#define NS 128
#define NV 64
#define TPC 192
#define NBASIS 16
#define HID 128
#define WOUT 384
#define NNODE 16000
#define NEDGE 256000
#define EPB 32

typedef __attribute__((ext_vector_type(8))) short bf16x8;
typedef __attribute__((ext_vector_type(8))) unsigned short u16x8;
typedef __attribute__((ext_vector_type(4))) float f32x4;

__device__ __forceinline__ float silu_f(float x) { return x / (1.0f + __expf(-x)); }
__device__ __forceinline__ unsigned short bf16b(float x) {
  __hip_bfloat16 h = __float2bfloat16(x);
  return *reinterpret_cast<unsigned short*>(&h);
}
__device__ __forceinline__ float bf2f(unsigned short u) {
  return __uint_as_float(((unsigned)u) << 16);
}

// ---------------- pack W1/W2 into MFMA B-fragment order (bf16) ----------------
__global__ __launch_bounds__(256) void pack_weights(
    const float* __restrict__ W1, const float* __restrict__ W2,
    unsigned short* __restrict__ W1P, unsigned short* __restrict__ W2P) {
  const int id = blockIdx.x * 256 + threadIdx.x;
  if (id < 24 * 4 * 64 * 8) {
    const int j = id & 7, lane = (id >> 3) & 63, k = (id >> 9) & 3, nt = id >> 11;
    const int krow = k * 32 + (lane >> 4) * 8 + j;
    const int ncol = nt * 16 + (lane & 15);
    W2P[id] = bf16b(W2[krow * WOUT + ncol]);
  }
  if (id < 8 * 64 * 8) {
    const int j = id & 7, lane = (id >> 3) & 63, nt = id >> 9;
    const int krow = (lane >> 4) * 8 + j;
    const int ncol = nt * 16 + (lane & 15);
    W1P[id] = (krow < NBASIS) ? bf16b(W1[krow * HID + ncol]) : (unsigned short)0;
  }
}

// ---------------- node_pre: 4 nodes/block ----------------
__global__ __launch_bounds__(256) void node_pre4(
    const float* __restrict__ node_feat, const float* __restrict__ Wps,
    const float* __restrict__ bps, const float* __restrict__ Wpv,
    float* __restrict__ x_s, float* __restrict__ x_v) {
  const int n0 = blockIdx.x * 4;
  const int t = threadIdx.x;
  __shared__ float s_sh[4][NS];
  __shared__ float v_sh[4][NV * 3];
  for (int i = t; i < 4 * 320; i += 256) {
    const int nn = i / 320, off = i - nn * 320;
    const float val = node_feat[(size_t)(n0 + nn) * 320 + off];
    if (off < NS) s_sh[nn][off] = val; else v_sh[nn][off - NS] = val;
  }
  __syncthreads();
  for (int o = t; o < 320; o += 256) {
    if (o < NS) {
      float a0 = 0.f, a1 = 0.f, a2 = 0.f, a3 = 0.f;
      #pragma unroll 8
      for (int u = 0; u < NS; ++u) {
        const float wv = Wps[u * NS + o];
        a0 = fmaf(s_sh[0][u], wv, a0); a1 = fmaf(s_sh[1][u], wv, a1);
        a2 = fmaf(s_sh[2][u], wv, a2); a3 = fmaf(s_sh[3][u], wv, a3);
      }
      const float b = bps[o];
      x_s[(size_t)(n0 + 0) * NS + o] = a0 * 0.08838834764831845f + b;
      x_s[(size_t)(n0 + 1) * NS + o] = a1 * 0.08838834764831845f + b;
      x_s[(size_t)(n0 + 2) * NS + o] = a2 * 0.08838834764831845f + b;
      x_s[(size_t)(n0 + 3) * NS + o] = a3 * 0.08838834764831845f + b;
    } else {
      const int q = o - NS;
      const int vch = q / 3, c = q - vch * 3;
      float a0 = 0.f, a1 = 0.f, a2 = 0.f, a3 = 0.f;
      #pragma unroll 8
      for (int u = 0; u < NV; ++u) {
        const float wv = Wpv[u * NV + vch];
        a0 = fmaf(v_sh[0][u * 3 + c], wv, a0); a1 = fmaf(v_sh[1][u * 3 + c], wv, a1);
        a2 = fmaf(v_sh[2][u * 3 + c], wv, a2); a3 = fmaf(v_sh[3][u * 3 + c], wv, a3);
      }
      x_v[(size_t)(n0 + 0) * (NV * 3) + q] = a0 * 0.125f;
      x_v[(size_t)(n0 + 1) * (NV * 3) + q] = a1 * 0.125f;
      x_v[(size_t)(n0 + 2) * (NV * 3) + q] = a2 * 0.125f;
      x_v[(size_t)(n0 + 3) * (NV * 3) + q] = a3 * 0.125f;
    }
  }
}

// ================= CSR build =================
__global__ void hist_kernel(const int* __restrict__ ei, int* __restrict__ cnt) {
  int e = blockIdx.x * 256 + threadIdx.x;
  if (e < NEDGE) atomicAdd(&cnt[ei[e]], 1);
}

__global__ __launch_bounds__(256) void scan_kernel(
    const int* __restrict__ cnt, int* __restrict__ row_start, int* __restrict__ cursor) {
  __shared__ int part[256];
  const int t = threadIdx.x;
  const int base = t * 63;
  int s = 0;
  for (int i = 0; i < 63; ++i) {
    int idx = base + i;
    if (idx < NNODE) s += cnt[idx];
  }
  part[t] = s;
  __syncthreads();
  if (t == 0) {
    int run = 0;
    for (int i = 0; i < 256; ++i) { int x = part[i]; part[i] = run; run += x; }
  }
  __syncthreads();
  int run = part[t];
  for (int i = 0; i < 63; ++i) {
    int idx = base + i;
    if (idx < NNODE) {
      int c = cnt[idx];   // read before overwrite (cnt aliases cursor)
      row_start[idx] = run;
      cursor[idx] = run;
      run += c;
    }
  }
  if (t == 255) row_start[NNODE] = run;
}

// scatter: assign CSR slot, record perm (edge->slot) and per-slot meta {src, r1}
__global__ void scatter_kernel(const int* __restrict__ ei,
                               const float* __restrict__ edge_rshs,
                               int* __restrict__ cursor, int* __restrict__ perm,
                               float4* __restrict__ meta) {
  int e = blockIdx.x * 256 + threadIdx.x;
  if (e < NEDGE) {
    int p = atomicAdd(&cursor[ei[e]], 1);
    perm[e] = p;
    float4 m;
    m.x = __int_as_float(ei[NEDGE + e]);
    m.y = edge_rshs[e * 4 + 1];
    m.z = edge_rshs[e * 4 + 2];
    m.w = edge_rshs[e * 4 + 3];
    meta[p] = m;
  }
}

// ================= edge MLP via MFMA -> bf16 messages at CSR slots ============
// msg layout per slot (384 bf16): [0:192)=msg_s  [192:320)=w_sv1*s_j  [320:384)=w_vs1*r0
__global__ __launch_bounds__(256) void edge_mlp_mfma(
    const float* __restrict__ edge_attr, const float* __restrict__ edge_rshs,
    const int* __restrict__ edge_index, const int* __restrict__ perm,
    const unsigned short* __restrict__ W1P, const float* __restrict__ b1,
    const unsigned short* __restrict__ W2P, const float* __restrict__ b2,
    const float* __restrict__ x_s, const float* __restrict__ x_v,
    unsigned short* __restrict__ msg) {
  // phase-separated union: {ea, Hs} live until A-frag preload; msg staging after
  union SMU {
    struct { unsigned short ea[32 * 48]; unsigned short Hs[32 * 136]; } p1;
    unsigned short msgb[32 * 392];
  };
  __shared__ __align__(16) SMU sm;
  __shared__ unsigned short sj[32][136];   // bf16 s_j rows
  __shared__ unsigned short vd[32][72];    // bf16 <v_j,r1>*inv_sqrt3
  __shared__ int src_sh[32];
  __shared__ int slot_sh[32];
  __shared__ float rsh_sh[32][4];
  const int t = threadIdx.x;
  const int lane = t & 63;
  const int w = t >> 6;
  const int l15 = lane & 15;
  const int l4 = lane >> 4;
  const int eblk = blockIdx.x * EPB;

  // ---- phase 0: stage edge_attr + metadata
  for (int i = t; i < 32 * 48; i += 256) {
    const int e = i / 48, k = i - e * 48;
    sm.p1.ea[i] = (k < NBASIS) ? bf16b(edge_attr[(size_t)(eblk + e) * NBASIS + k])
                               : (unsigned short)0;
  }
  if (t < 32 * 4) rsh_sh[t >> 2][t & 3] = edge_rshs[(size_t)eblk * 4 + t];
  if (t < 32) {
    src_sh[t] = edge_index[NEDGE + eblk + t];
    slot_sh[t] = perm[eblk + t];
  }
  __syncthreads();

  // ---- phase 1: GEMM1 (H = silu(ea@W1+b1)) + cooperative sj/vd staging
  {
    const int mt = w & 1, ch = w >> 1;
    const bf16x8 afrag = *(const bf16x8*)&sm.p1.ea[(mt * 16 + l15) * 48 + l4 * 8];
    #pragma unroll
    for (int nt = 0; nt < 4; ++nt) {
      const int ntg = ch * 4 + nt;
      const bf16x8 bfrag = *(const bf16x8*)&W1P[((size_t)ntg * 64 + lane) * 8];
      f32x4 d = {0.f, 0.f, 0.f, 0.f};
      d = __builtin_amdgcn_mfma_f32_16x16x32_bf16(afrag, bfrag, d, 0, 0, 0);
      const int col = ntg * 16 + l15;
      const float bias = b1[col];
      #pragma unroll
      for (int i = 0; i < 4; ++i) {
        const int e = mt * 16 + l4 * 4 + i;
        sm.p1.Hs[e * 136 + col] = bf16b(silu_f(d[i] + bias));
      }
    }
  }
  // stage s_j rows (coalesced f32 reads -> bf16 LDS)
  #pragma unroll
  for (int p = 0; p < 16; ++p) {
    const int idx = p * 256 + t;
    const int e = idx >> 7, c = idx & 127;
    sj[e][c] = bf16b(x_s[(size_t)src_sh[e] * NS + c]);
  }
  // stage vd[e][u] = <v_j[u], r1> * inv_sqrt3
  #pragma unroll
  for (int p = 0; p < 8; ++p) {
    const int idx = p * 256 + t;
    const int e = idx >> 6, u = idx & 63;
    const float* vp = x_v + (size_t)src_sh[e] * (NV * 3) + u * 3;
    const float dotv = vp[0] * rsh_sh[e][1] + vp[1] * rsh_sh[e][2] + vp[2] * rsh_sh[e][3];
    vd[e][u] = bf16b(dotv * 0.5773502691896258f);
  }
  __syncthreads();

  // ---- phase 2: preload A-frags from Hs (then Hs is dead)
  bf16x8 afr[2][4];
  #pragma unroll
  for (int mt = 0; mt < 2; ++mt)
    #pragma unroll
    for (int k = 0; k < 4; ++k)
      afr[mt][k] = *(const bf16x8*)&sm.p1.Hs[(mt * 16 + l15) * 136 + k * 32 + l4 * 8];

  float r0a[2][4];
  #pragma unroll
  for (int mt = 0; mt < 2; ++mt)
    #pragma unroll
    for (int i = 0; i < 4; ++i) r0a[mt][i] = rsh_sh[mt * 16 + l4 * 4 + i][0];
  __syncthreads();   // everyone done reading Hs; msgb region now writable

  // ---- phase 3: GEMM2 + in-LDS epilogue. wave w owns ntiles [w*6, w*6+6)
  for (int nn = 0; nn < 6; ++nn) {
    const int nt = w * 6 + nn;
    bf16x8 bfr[4];
    #pragma unroll
    for (int k = 0; k < 4; ++k)
      bfr[k] = *(const bf16x8*)&W2P[(((size_t)nt * 4 + k) * 64 + lane) * 8];
    f32x4 acc0 = {0.f, 0.f, 0.f, 0.f}, acc1 = {0.f, 0.f, 0.f, 0.f};
    #pragma unroll
    for (int k = 0; k < 4; ++k) {
      acc0 = __builtin_amdgcn_mfma_f32_16x16x32_bf16(afr[0][k], bfr[k], acc0, 0, 0, 0);
      acc1 = __builtin_amdgcn_mfma_f32_16x16x32_bf16(afr[1][k], bfr[k], acc1, 0, 0, 0);
    }
    const int col = nt * 16 + l15;
    const float bias = b2[col];
    if (col < NS) {                       // w_ss0 * s_j * r0
      #pragma unroll
      for (int mt = 0; mt < 2; ++mt)
        #pragma unroll
        for (int i = 0; i < 4; ++i) {
          const int e = mt * 16 + l4 * 4 + i;
          const float wv = (mt ? acc1[i] : acc0[i]) + bias;
          sm.msgb[e * 392 + col] = bf16b(wv * bf2f(sj[e][col]) * r0a[mt][i]);
        }
    } else if (col < NS + NV) {           // w_vv0 * <v_j,r1>/sqrt3
      const int u = col - NS;
      #pragma unroll
      for (int mt = 0; mt < 2; ++mt)
        #pragma unroll
        for (int i = 0; i < 4; ++i) {
          const int e = mt * 16 + l4 * 4 + i;
          const float wv = (mt ? acc1[i] : acc0[i]) + bias;
          sm.msgb[e * 392 + col] = bf16b(wv * bf2f(vd[e][u]));
        }
    } else if (col < 2 * NS + NV) {       // w_sv1 * s_j
      const int sjc = col - (NS + NV);
      #pragma unroll
      for (int mt = 0; mt < 2; ++mt)
        #pragma unroll
        for (int i = 0; i < 4; ++i) {
          const int e = mt * 16 + l4 * 4 + i;
          const float wv = (mt ? acc1[i] : acc0[i]) + bias;
          sm.msgb[e * 392 + col] = bf16b(wv * bf2f(sj[e][sjc]));
        }
    } else {                              // w_vs1 * r0
      #pragma unroll
      for (int mt = 0; mt < 2; ++mt)
        #pragma unroll
        for (int i = 0; i < 4; ++i) {
          const int e = mt * 16 + l4 * 4 + i;
          const float wv = (mt ? acc1[i] : acc0[i]) + bias;
          sm.msgb[e * 392 + col] = bf16b(wv * r0a[mt][i]);
        }
    }
  }
  __syncthreads();

  // ---- phase 4: coalesced write-out, 768 B per edge row at its CSR slot
  #pragma unroll
  for (int p = 0; p < 6; ++p) {
    const int idx = p * 256 + t;
    const int e = idx / 48, c = idx - e * 48;
    const u16x8 vv = *(const u16x8*)&sm.msgb[e * 392 + c * 8];
    *(u16x8*)&msg[(size_t)slot_sh[e] * 384 + c * 8] = vv;
  }
}

// ================= per-node gather: wave-specialized channel ownership =========
// wave 0: msg_s channels (0..191)      -> 3 loads + 3 adds / edge
// wave 1: kind1 rows u=0..63           -> 1 load + 3 FMA(r1) / edge
// wave 2: kind1 rows u=64..127         -> 1 load + 3 FMA(r1) / edge
// wave 3: kind2 rows u=0..63           -> 1 load + coalesced x_v row + 3 FMA / edge
__global__ __launch_bounds__(256) void node_gather_post(
    const unsigned short* __restrict__ msg, const int* __restrict__ row_start,
    const float4* __restrict__ meta, const float* __restrict__ x_s,
    const float* __restrict__ x_v, const float* __restrict__ Wqs,
    const float* __restrict__ Wqv, float* __restrict__ out) {
  const int n = blockIdx.x;
  const int t = threadIdx.x;
  const int wv = t >> 6, ln = t & 63;
  const int beg = row_start[n], end = row_start[n + 1];

  float a0 = 0.f, a1 = 0.f, a2 = 0.f;

  if (wv == 0) {
    const unsigned short* mp = msg + (size_t)beg * 384 + ln;
    for (int i = beg; i < end; ++i, mp += 384) {
      a0 += bf2f(mp[0]);
      a1 += bf2f(mp[64]);
      a2 += bf2f(mp[128]);
    }
  } else if (wv < 3) {
    const int u = (wv - 1) * 64 + ln;
    const unsigned short* mp = msg + (size_t)beg * 384 + 192 + u;
    for (int i = beg; i < end; ++i, mp += 384) {
      const float4 mt = meta[i];
      const float m = bf2f(mp[0]);
      a0 = fmaf(m, mt.y, a0);
      a1 = fmaf(m, mt.z, a1);
      a2 = fmaf(m, mt.w, a2);
    }
  } else {
    const unsigned short* mp = msg + (size_t)beg * 384 + 320 + ln;
    for (int i = beg; i < end; ++i, mp += 384) {
      const float4 mt = meta[i];
      const int src = __float_as_int(mt.x);
      const float m = bf2f(mp[0]);
      const float* vp = x_v + (size_t)src * (NV * 3) + ln * 3;
      a0 = fmaf(m, vp[0], a0);
      a1 = fmaf(m, vp[1], a1);
      a2 = fmaf(m, vp[2], a2);
    }
  }

  __shared__ float accsh[768];
  if (wv == 0) {
    accsh[ln] = a0; accsh[ln + 64] = a1; accsh[ln + 128] = a2;
  } else if (wv < 3) {
    const int base = 192 + ((wv - 1) * 64 + ln) * 3;
    accsh[base] = a0; accsh[base + 1] = a1; accsh[base + 2] = a2;
  } else {
    const int base = 192 + (128 + ln) * 3;
    accsh[base] = a0; accsh[base + 1] = a1; accsh[base + 2] = a2;
  }
  __syncthreads();

  __shared__ float gs[192];
  __shared__ float gv[576];
  if (t < 192) {
    gs[t] = silu_f(accsh[t]);
    const float vx = accsh[192 + 3 * t], vy = accsh[192 + 3 * t + 1], vz = accsh[192 + 3 * t + 2];
    const float nrm = sqrtf(fmaf(vx, vx, fmaf(vy, vy, vz * vz)) + 1e-12f);
    const float sg = 1.f / (1.f + __expf(-nrm));
    gv[3 * t] = vx * sg; gv[3 * t + 1] = vy * sg; gv[3 * t + 2] = vz * sg;
  }
  __syncthreads();

  float* orow = out + (size_t)n * 320;
  for (int o = t; o < 320; o += 256) {
    float a2r = 0.f;
    if (o < NS) {
      #pragma unroll 8
      for (int u = 0; u < TPC; ++u) a2r = fmaf(gs[u], Wqs[u * NS + o], a2r);
      orow[o] = x_s[(size_t)n * NS + o] + a2r * 0.07216878364870323f;
    } else {
      const int q = o - NS;
      const int vch = q / 3, c = q - vch * 3;
      #pragma unroll 8
      for (int u = 0; u < TPC; ++u) a2r = fmaf(gv[u * 3 + c], Wqv[u * NV + vch], a2r);
      orow[o] = x_v[(size_t)n * (NV * 3) + q] + a2r * 0.07216878364870323f;
    }
  }
}

extern "C" void kernel_launch(void* const* d_in, const int* in_sizes, int n_in,
                              void* d_out, int out_size, void* d_ws, size_t ws_size,
                              hipStream_t stream) {
  const float* node_feat = (const float*)d_in[0];
  const float* edge_attr = (const float*)d_in[1];
  const float* edge_rshs = (const float*)d_in[2];
  const int*   edge_index = (const int*)d_in[3];
  const float* Wps = (const float*)d_in[4];
  const float* bps = (const float*)d_in[5];
  const float* Wpv = (const float*)d_in[6];
  const float* W1  = (const float*)d_in[7];
  const float* b1  = (const float*)d_in[8];
  const float* W2  = (const float*)d_in[9];
  const float* b2  = (const float*)d_in[10];
  const float* Wqs = (const float*)d_in[11];
  const float* Wqv = (const float*)d_in[12];
  float* out = (float*)d_out;

  float* x_s = (float*)d_ws;                                            // 16000*128 f32
  float* x_v = x_s + (size_t)NNODE * NS;                                // 16000*192 f32
  unsigned short* msg = (unsigned short*)(x_v + (size_t)NNODE * NV * 3);// 256000*384 bf16
  unsigned short* W1P = msg + (size_t)NEDGE * 384;                      // 4096 bf16
  unsigned short* W2P = W1P + 8 * 64 * 8;                               // 49152 bf16
  float4* meta = (float4*)(W2P + 24 * 4 * 64 * 8);                      // NEDGE float4
  int* row_start = (int*)(meta + NEDGE);                                // NNODE+1
  int* cursor = row_start + (NNODE + 1);                                // NNODE
  int* perm = cursor + NNODE;                                           // NEDGE

  hipMemsetAsync(cursor, 0, NNODE * sizeof(int), stream);
  pack_weights<<<192, 256, 0, stream>>>(W1, W2, W1P, W2P);
  node_pre4<<<NNODE / 4, 256, 0, stream>>>(node_feat, Wps, bps, Wpv, x_s, x_v);
  hist_kernel<<<(NEDGE + 255) / 256, 256, 0, stream>>>(edge_index, cursor);
  scan_kernel<<<1, 256, 0, stream>>>(cursor, row_start, cursor);
  scatter_kernel<<<(NEDGE + 255) / 256, 256, 0, stream>>>(edge_index, edge_rshs,
      cursor, perm, meta);
  edge_mlp_mfma<<<NEDGE / EPB, 256, 0, stream>>>(edge_attr, edge_rshs, edge_index,
      perm, W1P, b1, W2P, b2, x_s, x_v, msg);
  node_gather_post<<<NNODE, 256, 0, stream>>>(msg, row_start, meta, x_s, x_v,
      Wqs, Wqv, out);
}

// Round 7
// 328.976 us; speedup vs baseline: 29.1843x; 1.2276x over previous
//
#include <hip/hip_runtime.h>
#include <hip/hip_bf16.h>

#define NS 128
#define NV 64
#define TPC 192
#define NBASIS 16
#define HID 128
#define WOUT 384
#define NNODE 16000
#define NEDGE 256000
#define EPB 32
#define GVPLANE 3072000   // 16000*192

typedef __attribute__((ext_vector_type(8))) short bf16x8;
typedef __attribute__((ext_vector_type(8))) unsigned short u16x8;
typedef __attribute__((ext_vector_type(4))) float f32x4;

__device__ __forceinline__ float silu_f(float x) { return x / (1.0f + __expf(-x)); }
__device__ __forceinline__ unsigned short bf16b(float x) {
  __hip_bfloat16 h = __float2bfloat16(x);
  return *reinterpret_cast<unsigned short*>(&h);
}
__device__ __forceinline__ float bf2f(unsigned short u) {
  return __uint_as_float(((unsigned)u) << 16);
}

// ------------- pack W1/W2/Wqs/Wqv into MFMA B-fragment order (bf16) -----------
__global__ __launch_bounds__(256) void pack_weights(
    const float* __restrict__ W1, const float* __restrict__ W2,
    const float* __restrict__ Wqs, const float* __restrict__ Wqv,
    unsigned short* __restrict__ W1P, unsigned short* __restrict__ W2P,
    unsigned short* __restrict__ WqsP, unsigned short* __restrict__ WqvP) {
  const int id = blockIdx.x * 256 + threadIdx.x;
  const int j = id & 7, lane = (id >> 3) & 63;
  const int kj = (lane >> 4) * 8 + j;       // k-offset within 32-chunk
  const int nc = lane & 15;                 // col within 16-tile
  if (id < 24 * 4 * 64 * 8) {               // W2P[nt24][kc4][lane][8]
    const int kc = (id >> 9) & 3, nt = id >> 11;
    W2P[id] = bf16b(W2[(kc * 32 + kj) * WOUT + nt * 16 + nc]);
  }
  if (id < 8 * 64 * 8) {                    // W1P[nt8][lane][8] (K=16 padded to 32)
    const int nt = id >> 9;
    W1P[id] = (kj < NBASIS) ? bf16b(W1[kj * HID + nt * 16 + nc]) : (unsigned short)0;
  }
  if (id < 8 * 6 * 64 * 8) {                // WqsP[nt8][kc6][lane][8]
    const int kc = (id >> 9) % 6, nt = id / (6 * 512);
    WqsP[id] = bf16b(Wqs[(kc * 32 + kj) * NS + nt * 16 + nc]);
  }
  if (id < 4 * 6 * 64 * 8) {                // WqvP[nt4][kc6][lane][8]
    const int kc = (id >> 9) % 6, nt = id / (6 * 512);
    WqvP[id] = bf16b(Wqv[(kc * 32 + kj) * NV + nt * 16 + nc]);
  }
}

// ---------------- node_pre: 4 nodes/block ----------------
__global__ __launch_bounds__(256) void node_pre4(
    const float* __restrict__ node_feat, const float* __restrict__ Wps,
    const float* __restrict__ bps, const float* __restrict__ Wpv,
    float* __restrict__ x_s, float* __restrict__ x_v) {
  const int n0 = blockIdx.x * 4;
  const int t = threadIdx.x;
  __shared__ float s_sh[4][NS];
  __shared__ float v_sh[4][NV * 3];
  for (int i = t; i < 4 * 320; i += 256) {
    const int nn = i / 320, off = i - nn * 320;
    const float val = node_feat[(size_t)(n0 + nn) * 320 + off];
    if (off < NS) s_sh[nn][off] = val; else v_sh[nn][off - NS] = val;
  }
  __syncthreads();
  for (int o = t; o < 320; o += 256) {
    if (o < NS) {
      float a0 = 0.f, a1 = 0.f, a2 = 0.f, a3 = 0.f;
      #pragma unroll 8
      for (int u = 0; u < NS; ++u) {
        const float wv = Wps[u * NS + o];
        a0 = fmaf(s_sh[0][u], wv, a0); a1 = fmaf(s_sh[1][u], wv, a1);
        a2 = fmaf(s_sh[2][u], wv, a2); a3 = fmaf(s_sh[3][u], wv, a3);
      }
      const float b = bps[o];
      x_s[(size_t)(n0 + 0) * NS + o] = a0 * 0.08838834764831845f + b;
      x_s[(size_t)(n0 + 1) * NS + o] = a1 * 0.08838834764831845f + b;
      x_s[(size_t)(n0 + 2) * NS + o] = a2 * 0.08838834764831845f + b;
      x_s[(size_t)(n0 + 3) * NS + o] = a3 * 0.08838834764831845f + b;
    } else {
      const int q = o - NS;
      const int vch = q / 3, c = q - vch * 3;
      float a0 = 0.f, a1 = 0.f, a2 = 0.f, a3 = 0.f;
      #pragma unroll 8
      for (int u = 0; u < NV; ++u) {
        const float wv = Wpv[u * NV + vch];
        a0 = fmaf(v_sh[0][u * 3 + c], wv, a0); a1 = fmaf(v_sh[1][u * 3 + c], wv, a1);
        a2 = fmaf(v_sh[2][u * 3 + c], wv, a2); a3 = fmaf(v_sh[3][u * 3 + c], wv, a3);
      }
      x_v[(size_t)(n0 + 0) * (NV * 3) + q] = a0 * 0.125f;
      x_v[(size_t)(n0 + 1) * (NV * 3) + q] = a1 * 0.125f;
      x_v[(size_t)(n0 + 2) * (NV * 3) + q] = a2 * 0.125f;
      x_v[(size_t)(n0 + 3) * (NV * 3) + q] = a3 * 0.125f;
    }
  }
}

// ================= CSR build =================
__global__ void hist_kernel(const int* __restrict__ ei, int* __restrict__ cnt) {
  int e = blockIdx.x * 256 + threadIdx.x;
  if (e < NEDGE) atomicAdd(&cnt[ei[e]], 1);
}

__global__ __launch_bounds__(256) void scan_kernel(
    const int* __restrict__ cnt, int* __restrict__ row_start, int* __restrict__ cursor) {
  __shared__ int part[256];
  const int t = threadIdx.x;
  const int base = t * 63;
  int s = 0;
  for (int i = 0; i < 63; ++i) {
    int idx = base + i;
    if (idx < NNODE) s += cnt[idx];
  }
  part[t] = s;
  __syncthreads();
  if (t == 0) {
    int run = 0;
    for (int i = 0; i < 256; ++i) { int x = part[i]; part[i] = run; run += x; }
  }
  __syncthreads();
  int run = part[t];
  for (int i = 0; i < 63; ++i) {
    int idx = base + i;
    if (idx < NNODE) {
      int c = cnt[idx];   // read before overwrite (cnt aliases cursor)
      row_start[idx] = run;
      cursor[idx] = run;
      run += c;
    }
  }
  if (t == 255) row_start[NNODE] = run;
}

__global__ void scatter_kernel(const int* __restrict__ ei,
                               const float* __restrict__ edge_rshs,
                               int* __restrict__ cursor, int* __restrict__ perm,
                               float4* __restrict__ meta) {
  int e = blockIdx.x * 256 + threadIdx.x;
  if (e < NEDGE) {
    int p = atomicAdd(&cursor[ei[e]], 1);
    perm[e] = p;
    float4 m;
    m.x = __int_as_float(ei[NEDGE + e]);
    m.y = edge_rshs[e * 4 + 1];
    m.z = edge_rshs[e * 4 + 2];
    m.w = edge_rshs[e * 4 + 3];
    meta[p] = m;
  }
}

// ================= edge MLP via MFMA -> bf16 messages at CSR slots ============
// msg layout per slot (384 bf16): [0:192)=msg_s  [192:320)=w_sv1*s_j  [320:384)=w_vs1*r0
__global__ __launch_bounds__(256) void edge_mlp_mfma(
    const float* __restrict__ edge_attr, const float* __restrict__ edge_rshs,
    const int* __restrict__ edge_index, const int* __restrict__ perm,
    const unsigned short* __restrict__ W1P, const float* __restrict__ b1,
    const unsigned short* __restrict__ W2P, const float* __restrict__ b2,
    const float* __restrict__ x_s, const float* __restrict__ x_v,
    unsigned short* __restrict__ msg) {
  union SMU {
    struct { unsigned short ea[32 * 48]; unsigned short Hs[32 * 136]; } p1;
    unsigned short msgb[32 * 392];
  };
  __shared__ __align__(16) SMU sm;
  __shared__ unsigned short sj[32][136];
  __shared__ unsigned short vd[32][72];
  __shared__ int src_sh[32];
  __shared__ int slot_sh[32];
  __shared__ float rsh_sh[32][4];
  const int t = threadIdx.x;
  const int lane = t & 63;
  const int w = t >> 6;
  const int l15 = lane & 15;
  const int l4 = lane >> 4;
  const int eblk = blockIdx.x * EPB;

  for (int i = t; i < 32 * 48; i += 256) {
    const int e = i / 48, k = i - e * 48;
    sm.p1.ea[i] = (k < NBASIS) ? bf16b(edge_attr[(size_t)(eblk + e) * NBASIS + k])
                               : (unsigned short)0;
  }
  if (t < 32 * 4) rsh_sh[t >> 2][t & 3] = edge_rshs[(size_t)eblk * 4 + t];
  if (t < 32) {
    src_sh[t] = edge_index[NEDGE + eblk + t];
    slot_sh[t] = perm[eblk + t];
  }
  __syncthreads();

  {
    const int mt = w & 1, ch = w >> 1;
    const bf16x8 afrag = *(const bf16x8*)&sm.p1.ea[(mt * 16 + l15) * 48 + l4 * 8];
    #pragma unroll
    for (int nt = 0; nt < 4; ++nt) {
      const int ntg = ch * 4 + nt;
      const bf16x8 bfrag = *(const bf16x8*)&W1P[((size_t)ntg * 64 + lane) * 8];
      f32x4 d = {0.f, 0.f, 0.f, 0.f};
      d = __builtin_amdgcn_mfma_f32_16x16x32_bf16(afrag, bfrag, d, 0, 0, 0);
      const int col = ntg * 16 + l15;
      const float bias = b1[col];
      #pragma unroll
      for (int i = 0; i < 4; ++i) {
        const int e = mt * 16 + l4 * 4 + i;
        sm.p1.Hs[e * 136 + col] = bf16b(silu_f(d[i] + bias));
      }
    }
  }
  #pragma unroll
  for (int p = 0; p < 16; ++p) {
    const int idx = p * 256 + t;
    const int e = idx >> 7, c = idx & 127;
    sj[e][c] = bf16b(x_s[(size_t)src_sh[e] * NS + c]);
  }
  #pragma unroll
  for (int p = 0; p < 8; ++p) {
    const int idx = p * 256 + t;
    const int e = idx >> 6, u = idx & 63;
    const float* vp = x_v + (size_t)src_sh[e] * (NV * 3) + u * 3;
    const float dotv = vp[0] * rsh_sh[e][1] + vp[1] * rsh_sh[e][2] + vp[2] * rsh_sh[e][3];
    vd[e][u] = bf16b(dotv * 0.5773502691896258f);
  }
  __syncthreads();

  bf16x8 afr[2][4];
  #pragma unroll
  for (int mt = 0; mt < 2; ++mt)
    #pragma unroll
    for (int k = 0; k < 4; ++k)
      afr[mt][k] = *(const bf16x8*)&sm.p1.Hs[(mt * 16 + l15) * 136 + k * 32 + l4 * 8];

  float r0a[2][4];
  #pragma unroll
  for (int mt = 0; mt < 2; ++mt)
    #pragma unroll
    for (int i = 0; i < 4; ++i) r0a[mt][i] = rsh_sh[mt * 16 + l4 * 4 + i][0];
  __syncthreads();

  for (int nn = 0; nn < 6; ++nn) {
    const int nt = w * 6 + nn;
    bf16x8 bfr[4];
    #pragma unroll
    for (int k = 0; k < 4; ++k)
      bfr[k] = *(const bf16x8*)&W2P[(((size_t)nt * 4 + k) * 64 + lane) * 8];
    f32x4 acc0 = {0.f, 0.f, 0.f, 0.f}, acc1 = {0.f, 0.f, 0.f, 0.f};
    #pragma unroll
    for (int k = 0; k < 4; ++k) {
      acc0 = __builtin_amdgcn_mfma_f32_16x16x32_bf16(afr[0][k], bfr[k], acc0, 0, 0, 0);
      acc1 = __builtin_amdgcn_mfma_f32_16x16x32_bf16(afr[1][k], bfr[k], acc1, 0, 0, 0);
    }
    const int col = nt * 16 + l15;
    const float bias = b2[col];
    if (col < NS) {
      #pragma unroll
      for (int mt = 0; mt < 2; ++mt)
        #pragma unroll
        for (int i = 0; i < 4; ++i) {
          const int e = mt * 16 + l4 * 4 + i;
          const float wv = (mt ? acc1[i] : acc0[i]) + bias;
          sm.msgb[e * 392 + col] = bf16b(wv * bf2f(sj[e][col]) * r0a[mt][i]);
        }
    } else if (col < NS + NV) {
      const int u = col - NS;
      #pragma unroll
      for (int mt = 0; mt < 2; ++mt)
        #pragma unroll
        for (int i = 0; i < 4; ++i) {
          const int e = mt * 16 + l4 * 4 + i;
          const float wv = (mt ? acc1[i] : acc0[i]) + bias;
          sm.msgb[e * 392 + col] = bf16b(wv * bf2f(vd[e][u]));
        }
    } else if (col < 2 * NS + NV) {
      const int sjc = col - (NS + NV);
      #pragma unroll
      for (int mt = 0; mt < 2; ++mt)
        #pragma unroll
        for (int i = 0; i < 4; ++i) {
          const int e = mt * 16 + l4 * 4 + i;
          const float wv = (mt ? acc1[i] : acc0[i]) + bias;
          sm.msgb[e * 392 + col] = bf16b(wv * bf2f(sj[e][sjc]));
        }
    } else {
      #pragma unroll
      for (int mt = 0; mt < 2; ++mt)
        #pragma unroll
        for (int i = 0; i < 4; ++i) {
          const int e = mt * 16 + l4 * 4 + i;
          const float wv = (mt ? acc1[i] : acc0[i]) + bias;
          sm.msgb[e * 392 + col] = bf16b(wv * r0a[mt][i]);
        }
    }
  }
  __syncthreads();

  #pragma unroll
  for (int p = 0; p < 6; ++p) {
    const int idx = p * 256 + t;
    const int e = idx / 48, c = idx - e * 48;
    const u16x8 vv = *(const u16x8*)&sm.msgb[e * 392 + c * 8];
    *(u16x8*)&msg[(size_t)slot_sh[e] * 384 + c * 8] = vv;
  }
}

// ===== node_gather: wave-specialized stream + in-register gates -> bf16 A mats ==
// wave 0: acc_s channels {ln, ln+64, ln+128} -> silu -> gs16[n][ch]
// wave 1/2: kind1 rows u=(wv-1)*64+ln  (full 3-vector per lane -> gate in-reg)
// wave 3:   kind2 rows u=128+ln
__global__ __launch_bounds__(256) void node_gather(
    const unsigned short* __restrict__ msg, const int* __restrict__ row_start,
    const float4* __restrict__ meta, const float* __restrict__ x_v,
    unsigned short* __restrict__ gs16, unsigned short* __restrict__ gv16) {
  const int n = blockIdx.x;
  const int t = threadIdx.x;
  const int wv = t >> 6, ln = t & 63;
  const int beg = row_start[n], end = row_start[n + 1];

  float a0 = 0.f, a1 = 0.f, a2 = 0.f;

  if (wv == 0) {
    const unsigned short* mp = msg + (size_t)beg * 384 + ln;
    for (int i = beg; i < end; ++i, mp += 384) {
      a0 += bf2f(mp[0]);
      a1 += bf2f(mp[64]);
      a2 += bf2f(mp[128]);
    }
    gs16[(size_t)n * 192 + ln]       = bf16b(silu_f(a0));
    gs16[(size_t)n * 192 + ln + 64]  = bf16b(silu_f(a1));
    gs16[(size_t)n * 192 + ln + 128] = bf16b(silu_f(a2));
  } else {
    if (wv < 3) {
      const unsigned short* mp = msg + (size_t)beg * 384 + 192 + (wv - 1) * 64 + ln;
      for (int i = beg; i < end; ++i, mp += 384) {
        const float4 mt = meta[i];
        const float m = bf2f(mp[0]);
        a0 = fmaf(m, mt.y, a0);
        a1 = fmaf(m, mt.z, a1);
        a2 = fmaf(m, mt.w, a2);
      }
    } else {
      const unsigned short* mp = msg + (size_t)beg * 384 + 320 + ln;
      for (int i = beg; i < end; ++i, mp += 384) {
        const float4 mt = meta[i];
        const int src = __float_as_int(mt.x);
        const float m = bf2f(mp[0]);
        const float* vp = x_v + (size_t)src * (NV * 3) + ln * 3;
        a0 = fmaf(m, vp[0], a0);
        a1 = fmaf(m, vp[1], a1);
        a2 = fmaf(m, vp[2], a2);
      }
    }
    const float nrm = sqrtf(fmaf(a0, a0, fmaf(a1, a1, a2 * a2)) + 1e-12f);
    const float sg = 1.f / (1.f + __expf(-nrm));
    const int u = (wv < 3) ? (wv - 1) * 64 + ln : 128 + ln;
    gv16[(size_t)0 * GVPLANE + (size_t)n * 192 + u] = bf16b(a0 * sg);
    gv16[(size_t)1 * GVPLANE + (size_t)n * 192 + u] = bf16b(a1 * sg);
    gv16[(size_t)2 * GVPLANE + (size_t)n * 192 + u] = bf16b(a2 * sg);
  }
}

// ===== node_post_mfma: 32 nodes/block, p_s/p_v GEMMs via MFMA + residual =======
__global__ __launch_bounds__(256) void node_post_mfma(
    const unsigned short* __restrict__ gs16, const unsigned short* __restrict__ gv16,
    const unsigned short* __restrict__ WqsP, const unsigned short* __restrict__ WqvP,
    const float* __restrict__ x_s, const float* __restrict__ x_v,
    float* __restrict__ out) {
  __shared__ __align__(16) unsigned short gsA[32 * 200];
  __shared__ __align__(16) unsigned short gvA[3][32 * 200];
  const int n0 = blockIdx.x * 32;
  const int t = threadIdx.x;
  const int lane = t & 63;
  const int w = t >> 6;
  const int l15 = lane & 15;
  const int l4 = lane >> 4;
  const float SC = 0.07216878364870323f;

  // stage A tiles (coalesced 16B chunks)
  {
    const unsigned short* sp = gs16 + (size_t)n0 * 192;
    for (int idx = t; idx < 768; idx += 256) {
      const int row = idx / 24, ch = idx - row * 24;
      *(u16x8*)&gsA[row * 200 + ch * 8] = *(const u16x8*)&sp[row * 192 + ch * 8];
    }
    #pragma unroll
    for (int c = 0; c < 3; ++c) {
      const unsigned short* vp = gv16 + (size_t)c * GVPLANE + (size_t)n0 * 192;
      for (int idx = t; idx < 768; idx += 256) {
        const int row = idx / 24, ch = idx - row * 24;
        *(u16x8*)&gvA[c][row * 200 + ch * 8] = *(const u16x8*)&vp[row * 192 + ch * 8];
      }
    }
  }
  __syncthreads();

  f32x4 accS[2][2];   // [nt-local][mt]
  f32x4 accV[3][2];   // [c][mt]
  #pragma unroll
  for (int j = 0; j < 2; ++j)
    #pragma unroll
    for (int mt = 0; mt < 2; ++mt) accS[j][mt] = (f32x4){0.f, 0.f, 0.f, 0.f};
  #pragma unroll
  for (int c = 0; c < 3; ++c)
    #pragma unroll
    for (int mt = 0; mt < 2; ++mt) accV[c][mt] = (f32x4){0.f, 0.f, 0.f, 0.f};

  #pragma unroll
  for (int kc = 0; kc < 6; ++kc) {
    bf16x8 aS[2], aV[3][2];
    #pragma unroll
    for (int mt = 0; mt < 2; ++mt)
      aS[mt] = *(const bf16x8*)&gsA[(mt * 16 + l15) * 200 + kc * 32 + l4 * 8];
    #pragma unroll
    for (int c = 0; c < 3; ++c)
      #pragma unroll
      for (int mt = 0; mt < 2; ++mt)
        aV[c][mt] = *(const bf16x8*)&gvA[c][(mt * 16 + l15) * 200 + kc * 32 + l4 * 8];
    const bf16x8 bS0 = *(const bf16x8*)&WqsP[(((size_t)(w * 2 + 0) * 6 + kc) * 64 + lane) * 8];
    const bf16x8 bS1 = *(const bf16x8*)&WqsP[(((size_t)(w * 2 + 1) * 6 + kc) * 64 + lane) * 8];
    const bf16x8 bV  = *(const bf16x8*)&WqvP[(((size_t)w * 6 + kc) * 64 + lane) * 8];
    #pragma unroll
    for (int mt = 0; mt < 2; ++mt) {
      accS[0][mt] = __builtin_amdgcn_mfma_f32_16x16x32_bf16(aS[mt], bS0, accS[0][mt], 0, 0, 0);
      accS[1][mt] = __builtin_amdgcn_mfma_f32_16x16x32_bf16(aS[mt], bS1, accS[1][mt], 0, 0, 0);
    }
    #pragma unroll
    for (int c = 0; c < 3; ++c)
      #pragma unroll
      for (int mt = 0; mt < 2; ++mt)
        accV[c][mt] = __builtin_amdgcn_mfma_f32_16x16x32_bf16(aV[c][mt], bV, accV[c][mt], 0, 0, 0);
  }

  // epilogue: p_s -> cols [0,128), p_v -> cols [128,320) as float3 per (row,vch)
  #pragma unroll
  for (int j = 0; j < 2; ++j) {
    const int col = (w * 2 + j) * 16 + l15;
    #pragma unroll
    for (int mt = 0; mt < 2; ++mt)
      #pragma unroll
      for (int i = 0; i < 4; ++i) {
        const int row = n0 + mt * 16 + l4 * 4 + i;
        out[(size_t)row * 320 + col] =
            x_s[(size_t)row * NS + col] + accS[j][mt][i] * SC;
      }
  }
  {
    const int vch = w * 16 + l15;
    #pragma unroll
    for (int mt = 0; mt < 2; ++mt)
      #pragma unroll
      for (int i = 0; i < 4; ++i) {
        const int row = n0 + mt * 16 + l4 * 4 + i;
        const float* xvp = x_v + (size_t)row * (NV * 3) + vch * 3;
        float o0 = xvp[0] + accV[0][mt][i] * SC;
        float o1 = xvp[1] + accV[1][mt][i] * SC;
        float o2 = xvp[2] + accV[2][mt][i] * SC;
        float* op = out + (size_t)row * 320 + NS + vch * 3;
        op[0] = o0; op[1] = o1; op[2] = o2;
      }
  }
}

extern "C" void kernel_launch(void* const* d_in, const int* in_sizes, int n_in,
                              void* d_out, int out_size, void* d_ws, size_t ws_size,
                              hipStream_t stream) {
  const float* node_feat = (const float*)d_in[0];
  const float* edge_attr = (const float*)d_in[1];
  const float* edge_rshs = (const float*)d_in[2];
  const int*   edge_index = (const int*)d_in[3];
  const float* Wps = (const float*)d_in[4];
  const float* bps = (const float*)d_in[5];
  const float* Wpv = (const float*)d_in[6];
  const float* W1  = (const float*)d_in[7];
  const float* b1  = (const float*)d_in[8];
  const float* W2  = (const float*)d_in[9];
  const float* b2  = (const float*)d_in[10];
  const float* Wqs = (const float*)d_in[11];
  const float* Wqv = (const float*)d_in[12];
  float* out = (float*)d_out;

  float* x_s = (float*)d_ws;                                            // 16000*128 f32
  float* x_v = x_s + (size_t)NNODE * NS;                                // 16000*192 f32
  unsigned short* msg = (unsigned short*)(x_v + (size_t)NNODE * NV * 3);// 256000*384 bf16
  unsigned short* W1P = msg + (size_t)NEDGE * 384;                      // 4096
  unsigned short* W2P = W1P + 8 * 64 * 8;                               // 49152
  unsigned short* WqsP = W2P + 24 * 4 * 64 * 8;                         // 24576
  unsigned short* WqvP = WqsP + 8 * 6 * 64 * 8;                         // 12288
  unsigned short* gs16 = WqvP + 4 * 6 * 64 * 8;                         // 3,072,000
  unsigned short* gv16 = gs16 + (size_t)GVPLANE;                        // 9,216,000
  float4* meta = (float4*)(gv16 + (size_t)3 * GVPLANE);                 // NEDGE float4
  int* row_start = (int*)(meta + NEDGE);                                // NNODE+1
  int* cursor = row_start + (NNODE + 1);                                // NNODE
  int* perm = cursor + NNODE;                                           // NEDGE

  hipMemsetAsync(cursor, 0, NNODE * sizeof(int), stream);
  pack_weights<<<192, 256, 0, stream>>>(W1, W2, Wqs, Wqv, W1P, W2P, WqsP, WqvP);
  node_pre4<<<NNODE / 4, 256, 0, stream>>>(node_feat, Wps, bps, Wpv, x_s, x_v);
  hist_kernel<<<(NEDGE + 255) / 256, 256, 0, stream>>>(edge_index, cursor);
  scan_kernel<<<1, 256, 0, stream>>>(cursor, row_start, cursor);
  scatter_kernel<<<(NEDGE + 255) / 256, 256, 0, stream>>>(edge_index, edge_rshs,
      cursor, perm, meta);
  edge_mlp_mfma<<<NEDGE / EPB, 256, 0, stream>>>(edge_attr, edge_rshs, edge_index,
      perm, W1P, b1, W2P, b2, x_s, x_v, msg);
  node_gather<<<NNODE, 256, 0, stream>>>(msg, row_start, meta, x_v, gs16, gv16);
  node_post_mfma<<<NNODE / 32, 256, 0, stream>>>(gs16, gv16, WqsP, WqvP,
      x_s, x_v, out);
}

// Round 8
// 305.501 us; speedup vs baseline: 31.4269x; 1.0768x over previous
//
#include <hip/hip_runtime.h>
#include <hip/hip_bf16.h>

#define NS 128
#define NV 64
#define TPC 192
#define NBASIS 16
#define HID 128
#define WOUT 384
#define NNODE 16000
#define NEDGE 256000
#define EPB 32
#define GVPLANE 3072000   // 16000*192
#define VPLANE  1024000   // 16000*64

typedef __attribute__((ext_vector_type(8))) short bf16x8;
typedef __attribute__((ext_vector_type(8))) unsigned short u16x8;
typedef __attribute__((ext_vector_type(4))) unsigned short u16x4;
typedef __attribute__((ext_vector_type(4))) float f32x4;

__device__ __forceinline__ float silu_f(float x) { return x / (1.0f + __expf(-x)); }
__device__ __forceinline__ unsigned short bf16b(float x) {
  __hip_bfloat16 h = __float2bfloat16(x);
  return *reinterpret_cast<unsigned short*>(&h);
}
__device__ __forceinline__ float bf2f(unsigned short u) {
  return __uint_as_float(((unsigned)u) << 16);
}

// ------------- pack W1/W2/Wqs/Wqv into MFMA B-fragment order (bf16) -----------
__global__ __launch_bounds__(256) void pack_weights(
    const float* __restrict__ W1, const float* __restrict__ W2,
    const float* __restrict__ Wqs, const float* __restrict__ Wqv,
    unsigned short* __restrict__ W1P, unsigned short* __restrict__ W2P,
    unsigned short* __restrict__ WqsP, unsigned short* __restrict__ WqvP) {
  const int id = blockIdx.x * 256 + threadIdx.x;
  const int j = id & 7, lane = (id >> 3) & 63;
  const int kj = (lane >> 4) * 8 + j;       // k-offset within 32-chunk
  const int nc = lane & 15;                 // col within 16-tile
  if (id < 24 * 4 * 64 * 8) {               // W2P[nt24][kc4][lane][8]
    const int kc = (id >> 9) & 3, nt = id >> 11;
    W2P[id] = bf16b(W2[(kc * 32 + kj) * WOUT + nt * 16 + nc]);
  }
  if (id < 8 * 64 * 8) {                    // W1P[nt8][lane][8] (K=16 padded to 32)
    const int nt = id >> 9;
    W1P[id] = (kj < NBASIS) ? bf16b(W1[kj * HID + nt * 16 + nc]) : (unsigned short)0;
  }
  if (id < 8 * 6 * 64 * 8) {                // WqsP[nt8][kc6][lane][8]
    const int kc = (id >> 9) % 6, nt = id / (6 * 512);
    WqsP[id] = bf16b(Wqs[(kc * 32 + kj) * NS + nt * 16 + nc]);
  }
  if (id < 4 * 6 * 64 * 8) {                // WqvP[nt4][kc6][lane][8]
    const int kc = (id >> 9) % 6, nt = id / (6 * 512);
    WqvP[id] = bf16b(Wqv[(kc * 32 + kj) * NV + nt * 16 + nc]);
  }
}

// -------- node_pre: 4 nodes/block; also emits bf16 x_s16 and xv16 planes ------
__global__ __launch_bounds__(256) void node_pre4(
    const float* __restrict__ node_feat, const float* __restrict__ Wps,
    const float* __restrict__ bps, const float* __restrict__ Wpv,
    float* __restrict__ x_s, float* __restrict__ x_v,
    unsigned short* __restrict__ x_s16, unsigned short* __restrict__ xv16) {
  const int n0 = blockIdx.x * 4;
  const int t = threadIdx.x;
  __shared__ float s_sh[4][NS];
  __shared__ float v_sh[4][NV * 3];
  for (int i = t; i < 4 * 320; i += 256) {
    const int nn = i / 320, off = i - nn * 320;
    const float val = node_feat[(size_t)(n0 + nn) * 320 + off];
    if (off < NS) s_sh[nn][off] = val; else v_sh[nn][off - NS] = val;
  }
  __syncthreads();
  for (int o = t; o < 320; o += 256) {
    if (o < NS) {
      float a0 = 0.f, a1 = 0.f, a2 = 0.f, a3 = 0.f;
      #pragma unroll 8
      for (int u = 0; u < NS; ++u) {
        const float wv = Wps[u * NS + o];
        a0 = fmaf(s_sh[0][u], wv, a0); a1 = fmaf(s_sh[1][u], wv, a1);
        a2 = fmaf(s_sh[2][u], wv, a2); a3 = fmaf(s_sh[3][u], wv, a3);
      }
      const float b = bps[o];
      const float r0 = a0 * 0.08838834764831845f + b;
      const float r1 = a1 * 0.08838834764831845f + b;
      const float r2 = a2 * 0.08838834764831845f + b;
      const float r3 = a3 * 0.08838834764831845f + b;
      x_s[(size_t)(n0 + 0) * NS + o] = r0; x_s16[(size_t)(n0 + 0) * NS + o] = bf16b(r0);
      x_s[(size_t)(n0 + 1) * NS + o] = r1; x_s16[(size_t)(n0 + 1) * NS + o] = bf16b(r1);
      x_s[(size_t)(n0 + 2) * NS + o] = r2; x_s16[(size_t)(n0 + 2) * NS + o] = bf16b(r2);
      x_s[(size_t)(n0 + 3) * NS + o] = r3; x_s16[(size_t)(n0 + 3) * NS + o] = bf16b(r3);
    } else {
      const int q = o - NS;
      const int vch = q / 3, c = q - vch * 3;
      float a0 = 0.f, a1 = 0.f, a2 = 0.f, a3 = 0.f;
      #pragma unroll 8
      for (int u = 0; u < NV; ++u) {
        const float wv = Wpv[u * NV + vch];
        a0 = fmaf(v_sh[0][u * 3 + c], wv, a0); a1 = fmaf(v_sh[1][u * 3 + c], wv, a1);
        a2 = fmaf(v_sh[2][u * 3 + c], wv, a2); a3 = fmaf(v_sh[3][u * 3 + c], wv, a3);
      }
      const float r0 = a0 * 0.125f, r1 = a1 * 0.125f, r2 = a2 * 0.125f, r3 = a3 * 0.125f;
      x_v[(size_t)(n0 + 0) * (NV * 3) + q] = r0;
      x_v[(size_t)(n0 + 1) * (NV * 3) + q] = r1;
      x_v[(size_t)(n0 + 2) * (NV * 3) + q] = r2;
      x_v[(size_t)(n0 + 3) * (NV * 3) + q] = r3;
      unsigned short* pl = xv16 + (size_t)c * VPLANE;
      pl[(size_t)(n0 + 0) * NV + vch] = bf16b(r0);
      pl[(size_t)(n0 + 1) * NV + vch] = bf16b(r1);
      pl[(size_t)(n0 + 2) * NV + vch] = bf16b(r2);
      pl[(size_t)(n0 + 3) * NV + vch] = bf16b(r3);
    }
  }
}

// ================= CSR build =================
__global__ void hist_kernel(const int* __restrict__ ei, int* __restrict__ cnt) {
  int e = blockIdx.x * 256 + threadIdx.x;
  if (e < NEDGE) atomicAdd(&cnt[ei[e]], 1);
}

__global__ __launch_bounds__(256) void scan_kernel(
    const int* __restrict__ cnt, int* __restrict__ row_start, int* __restrict__ cursor) {
  __shared__ int part[256];
  const int t = threadIdx.x;
  const int base = t * 63;
  int s = 0;
  for (int i = 0; i < 63; ++i) {
    int idx = base + i;
    if (idx < NNODE) s += cnt[idx];
  }
  part[t] = s;
  __syncthreads();
  if (t == 0) {
    int run = 0;
    for (int i = 0; i < 256; ++i) { int x = part[i]; part[i] = run; run += x; }
  }
  __syncthreads();
  int run = part[t];
  for (int i = 0; i < 63; ++i) {
    int idx = base + i;
    if (idx < NNODE) {
      int c = cnt[idx];   // read before overwrite (cnt aliases cursor)
      row_start[idx] = run;
      cursor[idx] = run;
      run += c;
    }
  }
  if (t == 255) row_start[NNODE] = run;
}

__global__ void scatter_kernel(const int* __restrict__ ei,
                               const float* __restrict__ edge_rshs,
                               int* __restrict__ cursor, int* __restrict__ perm,
                               float4* __restrict__ meta) {
  int e = blockIdx.x * 256 + threadIdx.x;
  if (e < NEDGE) {
    int p = atomicAdd(&cursor[ei[e]], 1);
    perm[e] = p;
    float4 m;
    m.x = __int_as_float(ei[NEDGE + e]);
    m.y = edge_rshs[e * 4 + 1];
    m.z = edge_rshs[e * 4 + 2];
    m.w = edge_rshs[e * 4 + 3];
    meta[p] = m;
  }
}

// ================= edge MLP via MFMA -> bf16 messages at CSR slots ============
// msg layout per slot (384 bf16): [0:192)=msg_s  [192:320)=w_sv1*s_j  [320:384)=w_vs1*r0
__global__ __launch_bounds__(256) void edge_mlp_mfma(
    const float* __restrict__ edge_attr, const float* __restrict__ edge_rshs,
    const int* __restrict__ edge_index, const int* __restrict__ perm,
    const unsigned short* __restrict__ W1P, const float* __restrict__ b1,
    const unsigned short* __restrict__ W2P, const float* __restrict__ b2,
    const unsigned short* __restrict__ x_s16, const unsigned short* __restrict__ xv16,
    unsigned short* __restrict__ msg) {
  union SMU {
    struct { unsigned short ea[32 * 48]; unsigned short Hs[32 * 136]; } p1;
    unsigned short msgb[32 * 392];
  };
  __shared__ __align__(16) SMU sm;
  __shared__ __align__(16) unsigned short sj[32][136];
  __shared__ __align__(16) unsigned short vd[32][72];
  __shared__ int src_sh[32];
  __shared__ int slot_sh[32];
  __shared__ float rsh_sh[32][4];
  const int t = threadIdx.x;
  const int lane = t & 63;
  const int w = t >> 6;
  const int l15 = lane & 15;
  const int l4 = lane >> 4;
  const int eblk = blockIdx.x * EPB;

  // ---- phase 0: metadata + vectorized ea staging (data: float4; pad: zeros)
  if (t < 32 * 4) rsh_sh[t >> 2][t & 3] = edge_rshs[(size_t)eblk * 4 + t];
  if (t < 32) {
    src_sh[t] = edge_index[NEDGE + eblk + t];
    slot_sh[t] = perm[eblk + t];
  }
  if (t < 128) {
    const int e = t >> 2, q = t & 3;
    const float4 v = *(const float4*)&edge_attr[(size_t)(eblk + e) * NBASIS + q * 4];
    u16x4 tmp;
    tmp[0] = bf16b(v.x); tmp[1] = bf16b(v.y); tmp[2] = bf16b(v.z); tmp[3] = bf16b(v.w);
    *(u16x4*)&sm.p1.ea[e * 48 + q * 4] = tmp;
  } else {
    const int idx = t - 128;           // 128 chunks × 8 shorts of K-pad
    const int e = idx >> 2, q = idx & 3;
    *(u16x8*)&sm.p1.ea[e * 48 + 16 + q * 8] = (u16x8){0, 0, 0, 0, 0, 0, 0, 0};
  }
  __syncthreads();

  // ---- phase 1: GEMM1 (H = silu(ea@W1+b1)) + sj/vd staging from bf16 sources
  {
    const int mt = w & 1, ch = w >> 1;
    const bf16x8 afrag = *(const bf16x8*)&sm.p1.ea[(mt * 16 + l15) * 48 + l4 * 8];
    #pragma unroll
    for (int nt = 0; nt < 4; ++nt) {
      const int ntg = ch * 4 + nt;
      const bf16x8 bfrag = *(const bf16x8*)&W1P[((size_t)ntg * 64 + lane) * 8];
      f32x4 d = {0.f, 0.f, 0.f, 0.f};
      d = __builtin_amdgcn_mfma_f32_16x16x32_bf16(afrag, bfrag, d, 0, 0, 0);
      const int col = ntg * 16 + l15;
      const float bias = b1[col];
      #pragma unroll
      for (int i = 0; i < 4; ++i) {
        const int e = mt * 16 + l4 * 4 + i;
        sm.p1.Hs[e * 136 + col] = bf16b(silu_f(d[i] + bias));
      }
    }
  }
  // sj: straight u16x8 copy from x_s16 (no conversions)
  #pragma unroll
  for (int p = 0; p < 2; ++p) {
    const int idx = p * 256 + t;
    const int e = idx >> 4, c8 = idx & 15;
    *(u16x8*)&sj[e][c8 * 8] =
        *(const u16x8*)&x_s16[(size_t)src_sh[e] * NS + c8 * 8];
  }
  // vd[e][u] = <v_j[u], r1> * inv_sqrt3 from bf16 planes
  #pragma unroll
  for (int p = 0; p < 8; ++p) {
    const int idx = p * 256 + t;
    const int e = idx >> 6, u = idx & 63;
    const size_t base = (size_t)src_sh[e] * NV + u;
    const float v0 = bf2f(xv16[base]);
    const float v1 = bf2f(xv16[VPLANE + base]);
    const float v2 = bf2f(xv16[2 * VPLANE + base]);
    const float dotv = fmaf(v0, rsh_sh[e][1], fmaf(v1, rsh_sh[e][2], v2 * rsh_sh[e][3]));
    vd[e][u] = bf16b(dotv * 0.5773502691896258f);
  }
  __syncthreads();

  // ---- phase 2: preload A-frags from Hs (then Hs is dead)
  bf16x8 afr[2][4];
  #pragma unroll
  for (int mt = 0; mt < 2; ++mt)
    #pragma unroll
    for (int k = 0; k < 4; ++k)
      afr[mt][k] = *(const bf16x8*)&sm.p1.Hs[(mt * 16 + l15) * 136 + k * 32 + l4 * 8];

  float r0a[2][4];
  #pragma unroll
  for (int mt = 0; mt < 2; ++mt)
    #pragma unroll
    for (int i = 0; i < 4; ++i) r0a[mt][i] = rsh_sh[mt * 16 + l4 * 4 + i][0];
  __syncthreads();

  // ---- phase 3: GEMM2 + in-LDS epilogue. wave w owns ntiles [w*6, w*6+6)
  for (int nn = 0; nn < 6; ++nn) {
    const int nt = w * 6 + nn;
    bf16x8 bfr[4];
    #pragma unroll
    for (int k = 0; k < 4; ++k)
      bfr[k] = *(const bf16x8*)&W2P[(((size_t)nt * 4 + k) * 64 + lane) * 8];
    f32x4 acc0 = {0.f, 0.f, 0.f, 0.f}, acc1 = {0.f, 0.f, 0.f, 0.f};
    #pragma unroll
    for (int k = 0; k < 4; ++k) {
      acc0 = __builtin_amdgcn_mfma_f32_16x16x32_bf16(afr[0][k], bfr[k], acc0, 0, 0, 0);
      acc1 = __builtin_amdgcn_mfma_f32_16x16x32_bf16(afr[1][k], bfr[k], acc1, 0, 0, 0);
    }
    const int col = nt * 16 + l15;
    const float bias = b2[col];
    if (col < NS) {
      #pragma unroll
      for (int mt = 0; mt < 2; ++mt)
        #pragma unroll
        for (int i = 0; i < 4; ++i) {
          const int e = mt * 16 + l4 * 4 + i;
          const float wv = (mt ? acc1[i] : acc0[i]) + bias;
          sm.msgb[e * 392 + col] = bf16b(wv * bf2f(sj[e][col]) * r0a[mt][i]);
        }
    } else if (col < NS + NV) {
      const int u = col - NS;
      #pragma unroll
      for (int mt = 0; mt < 2; ++mt)
        #pragma unroll
        for (int i = 0; i < 4; ++i) {
          const int e = mt * 16 + l4 * 4 + i;
          const float wv = (mt ? acc1[i] : acc0[i]) + bias;
          sm.msgb[e * 392 + col] = bf16b(wv * bf2f(vd[e][u]));
        }
    } else if (col < 2 * NS + NV) {
      const int sjc = col - (NS + NV);
      #pragma unroll
      for (int mt = 0; mt < 2; ++mt)
        #pragma unroll
        for (int i = 0; i < 4; ++i) {
          const int e = mt * 16 + l4 * 4 + i;
          const float wv = (mt ? acc1[i] : acc0[i]) + bias;
          sm.msgb[e * 392 + col] = bf16b(wv * bf2f(sj[e][sjc]));
        }
    } else {
      #pragma unroll
      for (int mt = 0; mt < 2; ++mt)
        #pragma unroll
        for (int i = 0; i < 4; ++i) {
          const int e = mt * 16 + l4 * 4 + i;
          const float wv = (mt ? acc1[i] : acc0[i]) + bias;
          sm.msgb[e * 392 + col] = bf16b(wv * r0a[mt][i]);
        }
    }
  }
  __syncthreads();

  // ---- phase 4: coalesced write-out, 768 B per edge row at its CSR slot
  #pragma unroll
  for (int p = 0; p < 6; ++p) {
    const int idx = p * 256 + t;
    const int e = idx / 48, c = idx - e * 48;
    const u16x8 vv = *(const u16x8*)&sm.msgb[e * 392 + c * 8];
    *(u16x8*)&msg[(size_t)slot_sh[e] * 384 + c * 8] = vv;
  }
}

// ===== node_gather: wave-specialized stream + in-register gates -> bf16 A mats ==
__global__ __launch_bounds__(256) void node_gather(
    const unsigned short* __restrict__ msg, const int* __restrict__ row_start,
    const float4* __restrict__ meta, const float* __restrict__ x_v,
    unsigned short* __restrict__ gs16, unsigned short* __restrict__ gv16) {
  const int n = blockIdx.x;
  const int t = threadIdx.x;
  const int wv = t >> 6, ln = t & 63;
  const int beg = row_start[n], end = row_start[n + 1];

  float a0 = 0.f, a1 = 0.f, a2 = 0.f;

  if (wv == 0) {
    const unsigned short* mp = msg + (size_t)beg * 384 + ln;
    for (int i = beg; i < end; ++i, mp += 384) {
      a0 += bf2f(mp[0]);
      a1 += bf2f(mp[64]);
      a2 += bf2f(mp[128]);
    }
    gs16[(size_t)n * 192 + ln]       = bf16b(silu_f(a0));
    gs16[(size_t)n * 192 + ln + 64]  = bf16b(silu_f(a1));
    gs16[(size_t)n * 192 + ln + 128] = bf16b(silu_f(a2));
  } else {
    if (wv < 3) {
      const unsigned short* mp = msg + (size_t)beg * 384 + 192 + (wv - 1) * 64 + ln;
      for (int i = beg; i < end; ++i, mp += 384) {
        const float4 mt = meta[i];
        const float m = bf2f(mp[0]);
        a0 = fmaf(m, mt.y, a0);
        a1 = fmaf(m, mt.z, a1);
        a2 = fmaf(m, mt.w, a2);
      }
    } else {
      const unsigned short* mp = msg + (size_t)beg * 384 + 320 + ln;
      for (int i = beg; i < end; ++i, mp += 384) {
        const float4 mt = meta[i];
        const int src = __float_as_int(mt.x);
        const float m = bf2f(mp[0]);
        const float* vp = x_v + (size_t)src * (NV * 3) + ln * 3;
        a0 = fmaf(m, vp[0], a0);
        a1 = fmaf(m, vp[1], a1);
        a2 = fmaf(m, vp[2], a2);
      }
    }
    const float nrm = sqrtf(fmaf(a0, a0, fmaf(a1, a1, a2 * a2)) + 1e-12f);
    const float sg = 1.f / (1.f + __expf(-nrm));
    const int u = (wv < 3) ? (wv - 1) * 64 + ln : 128 + ln;
    gv16[(size_t)0 * GVPLANE + (size_t)n * 192 + u] = bf16b(a0 * sg);
    gv16[(size_t)1 * GVPLANE + (size_t)n * 192 + u] = bf16b(a1 * sg);
    gv16[(size_t)2 * GVPLANE + (size_t)n * 192 + u] = bf16b(a2 * sg);
  }
}

// ===== node_post_mfma: 32 nodes/block, p_s/p_v GEMMs via MFMA + residual =======
__global__ __launch_bounds__(256) void node_post_mfma(
    const unsigned short* __restrict__ gs16, const unsigned short* __restrict__ gv16,
    const unsigned short* __restrict__ WqsP, const unsigned short* __restrict__ WqvP,
    const float* __restrict__ x_s, const float* __restrict__ x_v,
    float* __restrict__ out) {
  __shared__ __align__(16) unsigned short gsA[32 * 200];
  __shared__ __align__(16) unsigned short gvA[3][32 * 200];
  const int n0 = blockIdx.x * 32;
  const int t = threadIdx.x;
  const int lane = t & 63;
  const int w = t >> 6;
  const int l15 = lane & 15;
  const int l4 = lane >> 4;
  const float SC = 0.07216878364870323f;

  {
    const unsigned short* sp = gs16 + (size_t)n0 * 192;
    for (int idx = t; idx < 768; idx += 256) {
      const int row = idx / 24, ch = idx - row * 24;
      *(u16x8*)&gsA[row * 200 + ch * 8] = *(const u16x8*)&sp[row * 192 + ch * 8];
    }
    #pragma unroll
    for (int c = 0; c < 3; ++c) {
      const unsigned short* vp = gv16 + (size_t)c * GVPLANE + (size_t)n0 * 192;
      for (int idx = t; idx < 768; idx += 256) {
        const int row = idx / 24, ch = idx - row * 24;
        *(u16x8*)&gvA[c][row * 200 + ch * 8] = *(const u16x8*)&vp[row * 192 + ch * 8];
      }
    }
  }
  __syncthreads();

  f32x4 accS[2][2];
  f32x4 accV[3][2];
  #pragma unroll
  for (int j = 0; j < 2; ++j)
    #pragma unroll
    for (int mt = 0; mt < 2; ++mt) accS[j][mt] = (f32x4){0.f, 0.f, 0.f, 0.f};
  #pragma unroll
  for (int c = 0; c < 3; ++c)
    #pragma unroll
    for (int mt = 0; mt < 2; ++mt) accV[c][mt] = (f32x4){0.f, 0.f, 0.f, 0.f};

  #pragma unroll
  for (int kc = 0; kc < 6; ++kc) {
    bf16x8 aS[2], aV[3][2];
    #pragma unroll
    for (int mt = 0; mt < 2; ++mt)
      aS[mt] = *(const bf16x8*)&gsA[(mt * 16 + l15) * 200 + kc * 32 + l4 * 8];
    #pragma unroll
    for (int c = 0; c < 3; ++c)
      #pragma unroll
      for (int mt = 0; mt < 2; ++mt)
        aV[c][mt] = *(const bf16x8*)&gvA[c][(mt * 16 + l15) * 200 + kc * 32 + l4 * 8];
    const bf16x8 bS0 = *(const bf16x8*)&WqsP[(((size_t)(w * 2 + 0) * 6 + kc) * 64 + lane) * 8];
    const bf16x8 bS1 = *(const bf16x8*)&WqsP[(((size_t)(w * 2 + 1) * 6 + kc) * 64 + lane) * 8];
    const bf16x8 bV  = *(const bf16x8*)&WqvP[(((size_t)w * 6 + kc) * 64 + lane) * 8];
    #pragma unroll
    for (int mt = 0; mt < 2; ++mt) {
      accS[0][mt] = __builtin_amdgcn_mfma_f32_16x16x32_bf16(aS[mt], bS0, accS[0][mt], 0, 0, 0);
      accS[1][mt] = __builtin_amdgcn_mfma_f32_16x16x32_bf16(aS[mt], bS1, accS[1][mt], 0, 0, 0);
    }
    #pragma unroll
    for (int c = 0; c < 3; ++c)
      #pragma unroll
      for (int mt = 0; mt < 2; ++mt)
        accV[c][mt] = __builtin_amdgcn_mfma_f32_16x16x32_bf16(aV[c][mt], bV, accV[c][mt], 0, 0, 0);
  }

  #pragma unroll
  for (int j = 0; j < 2; ++j) {
    const int col = (w * 2 + j) * 16 + l15;
    #pragma unroll
    for (int mt = 0; mt < 2; ++mt)
      #pragma unroll
      for (int i = 0; i < 4; ++i) {
        const int row = n0 + mt * 16 + l4 * 4 + i;
        out[(size_t)row * 320 + col] =
            x_s[(size_t)row * NS + col] + accS[j][mt][i] * SC;
      }
  }
  {
    const int vch = w * 16 + l15;
    #pragma unroll
    for (int mt = 0; mt < 2; ++mt)
      #pragma unroll
      for (int i = 0; i < 4; ++i) {
        const int row = n0 + mt * 16 + l4 * 4 + i;
        const float* xvp = x_v + (size_t)row * (NV * 3) + vch * 3;
        float o0 = xvp[0] + accV[0][mt][i] * SC;
        float o1 = xvp[1] + accV[1][mt][i] * SC;
        float o2 = xvp[2] + accV[2][mt][i] * SC;
        float* op = out + (size_t)row * 320 + NS + vch * 3;
        op[0] = o0; op[1] = o1; op[2] = o2;
      }
  }
}

extern "C" void kernel_launch(void* const* d_in, const int* in_sizes, int n_in,
                              void* d_out, int out_size, void* d_ws, size_t ws_size,
                              hipStream_t stream) {
  const float* node_feat = (const float*)d_in[0];
  const float* edge_attr = (const float*)d_in[1];
  const float* edge_rshs = (const float*)d_in[2];
  const int*   edge_index = (const int*)d_in[3];
  const float* Wps = (const float*)d_in[4];
  const float* bps = (const float*)d_in[5];
  const float* Wpv = (const float*)d_in[6];
  const float* W1  = (const float*)d_in[7];
  const float* b1  = (const float*)d_in[8];
  const float* W2  = (const float*)d_in[9];
  const float* b2  = (const float*)d_in[10];
  const float* Wqs = (const float*)d_in[11];
  const float* Wqv = (const float*)d_in[12];
  float* out = (float*)d_out;

  float* x_s = (float*)d_ws;                                            // 16000*128 f32
  float* x_v = x_s + (size_t)NNODE * NS;                                // 16000*192 f32
  unsigned short* msg = (unsigned short*)(x_v + (size_t)NNODE * NV * 3);// 256000*384 bf16
  unsigned short* W1P = msg + (size_t)NEDGE * 384;                      // 4096
  unsigned short* W2P = W1P + 8 * 64 * 8;                               // 49152
  unsigned short* WqsP = W2P + 24 * 4 * 64 * 8;                         // 24576
  unsigned short* WqvP = WqsP + 8 * 6 * 64 * 8;                         // 12288
  unsigned short* x_s16 = WqvP + 4 * 6 * 64 * 8;                        // 2,048,000
  unsigned short* xv16 = x_s16 + (size_t)NNODE * NS;                    // 3,072,000
  unsigned short* gs16 = xv16 + (size_t)3 * VPLANE;                     // 3,072,000
  unsigned short* gv16 = gs16 + (size_t)NNODE * 192;                    // 9,216,000
  float4* meta = (float4*)(gv16 + (size_t)3 * GVPLANE);                 // NEDGE float4
  int* row_start = (int*)(meta + NEDGE);                                // NNODE+1
  int* cursor = row_start + (NNODE + 1);                                // NNODE
  int* perm = cursor + NNODE;                                           // NEDGE

  hipMemsetAsync(cursor, 0, NNODE * sizeof(int), stream);
  pack_weights<<<192, 256, 0, stream>>>(W1, W2, Wqs, Wqv, W1P, W2P, WqsP, WqvP);
  node_pre4<<<NNODE / 4, 256, 0, stream>>>(node_feat, Wps, bps, Wpv, x_s, x_v,
      x_s16, xv16);
  hist_kernel<<<(NEDGE + 255) / 256, 256, 0, stream>>>(edge_index, cursor);
  scan_kernel<<<1, 256, 0, stream>>>(cursor, row_start, cursor);
  scatter_kernel<<<(NEDGE + 255) / 256, 256, 0, stream>>>(edge_index, edge_rshs,
      cursor, perm, meta);
  edge_mlp_mfma<<<NEDGE / EPB, 256, 0, stream>>>(edge_attr, edge_rshs, edge_index,
      perm, W1P, b1, W2P, b2, x_s16, xv16, msg);
  node_gather<<<NNODE, 256, 0, stream>>>(msg, row_start, meta, x_v, gs16, gv16);
  node_post_mfma<<<NNODE / 32, 256, 0, stream>>>(gs16, gv16, WqsP, WqvP,
      x_s, x_v, out);
}